// Round 5
// baseline (413.433 us; speedup 1.0000x reference)
//
#include <hip/hip_runtime.h>

#define NN 100000
#define FF 128
#define HH 64
#define CC 16
#define EE 1000000
#define NSEG (2*NN)                 // segments: [0,NN) = fwd, [NN,2NN) = rev
#define BSH 11                      // bucket = d >> 11 (2048 dsts/bucket)
#define BKD  (1 << BSH)
#define NBUK ((NSEG + BKD - 1) / BKD)   // 98
#define EPB 4096                    // edges per fillA/bucket_count block
#define P1BLK ((2*EE + EPB - 1) / EPB)

typedef __bf16 bf16;
typedef __attribute__((ext_vector_type(8))) __bf16 bf16x8;
typedef __attribute__((ext_vector_type(4))) __bf16 bf16x4;
typedef __attribute__((ext_vector_type(4))) float f32x4;
typedef __attribute__((ext_vector_type(2))) float f32x2;

__device__ __forceinline__ float fsig(float t)  { return 1.0f/(1.0f+__expf(-t)); }
__device__ __forceinline__ float ftanh(float t) { return 1.0f - 2.0f/(__expf(2.0f*t)+1.0f); }

// ---- Combined weights in bf16 + bf16 copies of W_first / W_lin1 / W_out
__global__ void precomp_kernel(const float* __restrict__ W_ih, const float* __restrict__ b_ih,
                               const float* __restrict__ Wc1,  const float* __restrict__ bc1,
                               const float* __restrict__ Wc2,  const float* __restrict__ bc2,
                               const float* __restrict__ W_hh, const float* __restrict__ W_first,
                               const float* __restrict__ W_lin1, const float* __restrict__ W_out,
                               bf16* __restrict__ W1bf, float* __restrict__ b1,
                               bf16* __restrict__ W2bf, float* __restrict__ b2,
                               bf16* __restrict__ Whbf, bf16* __restrict__ Wfbf,
                               bf16* __restrict__ Wlbf, bf16* __restrict__ Wobf)
{
    int idx = blockIdx.x*blockDim.x + threadIdx.x;
    const int t0 = 192*128;          // W1/W2
    const int t1 = t0 + 192;         // b1/b2
    const int t2 = t1 + 192*64;      // Whbf
    const int t3 = t2 + 64*128;      // Wfbf
    const int t4 = t3 + 64*64;       // Wlbf
    const int t5 = t4 + 16*64;       // Wobf
    if (idx < t0) {
        int j = idx >> 7, k = idx & 127;
        float s1 = 0.f, s2 = 0.f;
        for (int m=0; m<64; ++m) {
            float wih = W_ih[j*64+m];
            s1 += wih * Wc1[m*128+k];
            s2 += wih * Wc2[m*128+k];
        }
        W1bf[idx] = (bf16)s1; W2bf[idx] = (bf16)s2;
    } else if (idx < t1) {
        int j = idx - t0;
        float s1 = b_ih[j], s2 = b_ih[j];
        for (int m=0; m<64; ++m) {
            float wih = W_ih[j*64+m];
            s1 += wih * bc1[m];
            s2 += wih * bc2[m];
        }
        b1[j] = s1; b2[j] = s2;
    } else if (idx < t2) {
        int i = idx - t1;  Whbf[i] = (bf16)W_hh[i];
    } else if (idx < t3) {
        int i = idx - t2;  Wfbf[i] = (bf16)W_first[i];
    } else if (idx < t4) {
        int i = idx - t3;  Wlbf[i] = (bf16)W_lin1[i];
    } else if (idx < t5) {
        int i = idx - t4;  Wobf[i] = (bf16)W_out[i];
    }
}

// ================= CSR build: bucketed 2-phase sort =================

__global__ __launch_bounds__(256) void bucket_count_kernel(const int* __restrict__ ei,
                                                           const int* __restrict__ ei_re,
                                                           int* __restrict__ bkcnt)
{
    __shared__ int hist[NBUK];
    const int t = threadIdx.x;
    for (int i=t; i<NBUK; i+=256) hist[i] = 0;
    __syncthreads();
    const long e0 = (long)blockIdx.x * EPB;
    #pragma unroll
    for (int it=0; it<16; ++it) {
        long e = e0 + it*256 + t;
        int d = -1;
        if (e < EE)        d = ei[EE + e];
        else if (e < 2*EE) d = NN + ei_re[EE + (e - EE)];
        if (d >= 0) atomicAdd(&hist[d >> BSH], 1);
    }
    __syncthreads();
    for (int i=t; i<NBUK; i+=256) if (hist[i]) atomicAdd(&bkcnt[i], hist[i]);
}

// parallel 128-thread scan of the 98 bucket counts
__global__ void bucket_scan_kernel(const int* __restrict__ bkcnt,
                                   int* __restrict__ bkbase, int* __restrict__ bkcur,
                                   int* __restrict__ rp)
{
    __shared__ int sc[128];
    const int t = threadIdx.x;      // 128 threads
    int v = (t < NBUK) ? bkcnt[t] : 0;
    sc[t] = v;
    __syncthreads();
    #pragma unroll
    for (int off=1; off<128; off<<=1) {
        int x = (t>=off) ? sc[t-off] : 0;
        __syncthreads();
        sc[t] += x;
        __syncthreads();
    }
    int excl = sc[t] - v;
    if (t < NBUK) { bkbase[t] = excl; bkcur[t] = excl; }
    if (t == NBUK-1) bkbase[NBUK] = sc[t];   // = 2E
    if (t == 0) rp[NSEG] = 2*EE;
}

__global__ __launch_bounds__(256) void fillA_kernel(const int* __restrict__ ei,
                                                    const float* __restrict__ ew,
                                                    const int* __restrict__ ei_re,
                                                    const float* __restrict__ ew_re,
                                                    int* __restrict__ bkcur,
                                                    int* __restrict__ tmp_d,
                                                    uint2* __restrict__ tmp_p)
{
    __shared__ int hist[NBUK];
    __shared__ int base[NBUK];
    const int t = threadIdx.x;
    for (int i=t; i<NBUK; i+=256) hist[i] = 0;
    __syncthreads();
    const long e0 = (long)blockIdx.x * EPB;
    int pr[16];
    #pragma unroll
    for (int it=0; it<16; ++it) {
        long e = e0 + it*256 + t;
        int d = -1;
        if (e < EE)        d = ei[EE + e];
        else if (e < 2*EE) d = NN + ei_re[EE + (e - EE)];
        if (d >= 0) {
            int b = d >> BSH;
            int r = atomicAdd(&hist[b], 1);
            pr[it] = (b << 16) | r;
        } else pr[it] = -1;
    }
    __syncthreads();
    for (int i=t; i<NBUK; i+=256) base[i] = atomicAdd(&bkcur[i], hist[i]);
    __syncthreads();
    #pragma unroll
    for (int it=0; it<16; ++it) {
        if (pr[it] < 0) continue;
        long e = e0 + it*256 + t;
        int d, s; float w;
        if (e < EE) { d = ei[EE+e]; s = ei[e]; w = ew[e]; }
        else { long j = e - EE; d = NN + ei_re[EE+j]; s = ei_re[j]; w = ew_re[j]; }
        int pos = base[pr[it] >> 16] + (pr[it] & 0xFFFF);
        tmp_d[pos] = d;
        // 8B edge record: {byte offset of src row in X, fp32 weight bits}
        tmp_p[pos] = make_uint2((unsigned)s * 128u, __float_as_uint(w));
    }
}

__global__ __launch_bounds__(1024) void fillB_kernel(const int* __restrict__ bkbase,
                                                     const int* __restrict__ tmp_d,
                                                     const uint2* __restrict__ tmp_p,
                                                     uint2* __restrict__ edata,
                                                     int* __restrict__ rp)
{
    __shared__ int cntL[BKD];      // counts -> later global cursors
    __shared__ int scanL[1024];
    const int t  = threadIdx.x;
    const int b  = blockIdx.x;
    const int d0 = b << BSH;
    const int dn = min(BKD, NSEG - d0);
    const int p0 = bkbase[b];
    const int p1 = bkbase[b+1];
    // safe overread pad past the end of edata (voff=0 -> row 0, w=0)
    if (b == 0 && t < 16) edata[2*EE + t] = make_uint2(0u, 0u);
    for (int i=t; i<BKD; i+=1024) cntL[i] = 0;
    __syncthreads();
    for (int pos = p0 + t; pos < p1; pos += 1024)
        atomicAdd(&cntL[tmp_d[pos] - d0], 1);
    __syncthreads();
    int a0 = cntL[2*t], a1 = cntL[2*t+1];
    int ps = a0 + a1;
    scanL[t] = ps;
    __syncthreads();
    #pragma unroll
    for (int off=1; off<1024; off<<=1) {
        int x = (t>=off) ? scanL[t-off] : 0;
        __syncthreads();
        scanL[t] += x;
        __syncthreads();
    }
    int g0 = p0 + scanL[t] - ps;
    int g1 = g0 + a0;
    if (2*t   < dn) rp[d0 + 2*t]   = g0;
    if (2*t+1 < dn) rp[d0 + 2*t+1] = g1;
    cntL[2*t]   = g0;
    cntL[2*t+1] = g1;
    __syncthreads();
    for (int pos = p0 + t; pos < p1; pos += 1024) {
        int d = tmp_d[pos];
        int p = atomicAdd(&cntL[d - d0], 1);
        edata[p] = tmp_p[pos];
    }
}

// Quarter-wave gather segment-sum, 4-deep, DECODE-FREE records (R13):
//  - 8B edge record {voff = src*128, w fp32}: no shifts to recover src/w
//  - voff is UNMASKED: overread slots (eq >= e1, <=15) read the next
//    segment's valid records, or the 16-entry zero pad at edata end —
//    every record's voff is a valid, 8B-aligned X offset; w is masked 0
//  - 4 independent X gathers in flight (R11/R12: fewer => latency-bound)
//  - bf16->f32 via <<16 / &0xFFFF0000 pairs, float2 accum (v_pk_fma_f32)
__global__ __launch_bounds__(256) void csr_prop_kernel(const bf16* __restrict__ X,
    const int* __restrict__ rp, const uint2* __restrict__ edata,
    bf16* __restrict__ x1, bf16* __restrict__ x2)
{
    int s = blockIdx.x*4 + (threadIdx.x>>6);
    if (s >= NSEG) return;
    const int lane = threadIdx.x & 63;
    const int q  = lane >> 4;      // edge slot 0..3
    const int fl = lane & 15;      // feature group: 4fl .. 4fl+3
    const unsigned foff = 8u*(unsigned)fl;
    const int e0 = rp[s], e1 = rp[s+1];
    const char* Xb = (const char*)X;
    const char* Eb = (const char*)edata;

    f32x2 acc01 = {0.f, 0.f}, acc23 = {0.f, 0.f};
    int eq = e0 + q;
    unsigned eqb = 8u*(unsigned)eq;
    for (int base = e0; base < e1; base += 16, eq += 16, eqb += 128u) {
        const int rem = e1 - eq;
        uint2 pk[4];
        #pragma unroll
        for (int j=0; j<4; ++j)
            pk[j] = *(const uint2*)(Eb + (eqb + 32u*(unsigned)j));
        uint2 dv[4];
        #pragma unroll
        for (int j=0; j<4; ++j)
            dv[j] = *(const uint2*)(Xb + (pk[j].x | foff));
        #pragma unroll
        for (int j=0; j<4; ++j) {
            float w = (4*j < rem) ? __uint_as_float(pk[j].y) : 0.f;
            f32x2 w2 = { w, w };
            acc01 += w2 * (f32x2){ __uint_as_float(dv[j].x << 16), __uint_as_float(dv[j].x & 0xFFFF0000u) };
            acc23 += w2 * (f32x2){ __uint_as_float(dv[j].y << 16), __uint_as_float(dv[j].y & 0xFFFF0000u) };
        }
    }
    float a0 = acc01.x, a1 = acc01.y, a2 = acc23.x, a3 = acc23.y;
    // reduce across the 4 quarters (lanes with equal fl)
    a0 += __shfl_xor(a0, 32); a0 += __shfl_xor(a0, 16);
    a1 += __shfl_xor(a1, 32); a1 += __shfl_xor(a1, 16);
    a2 += __shfl_xor(a2, 32); a2 += __shfl_xor(a2, 16);
    a3 += __shfl_xor(a3, 32); a3 += __shfl_xor(a3, 16);
    if (q == 0) {
        bf16* o = (s < NN) ? &x1[(long)s*HH] : &x2[(long)(s-NN)*HH];
        bf16x4 ov = {(bf16)a0, (bf16)a1, (bf16)a2, (bf16)a3};
        *(bf16x4*)&o[4*fl] = ov;
    }
}

// ================= dense kernels: all MFMA =================

__global__ __launch_bounds__(256, 2) void lin_first_mfma_kernel(
    const float* __restrict__ X, const bf16* __restrict__ Wf,
    const float* __restrict__ b, float* __restrict__ Y, bf16* __restrict__ Ybf)
{
    const int t = threadIdx.x;
    const int w = t >> 6, lane = t & 63, col = lane & 15, quad = lane >> 4;
    bf16x8 B[4];
    #pragma unroll
    for (int ks=0; ks<4; ++ks)
        B[ks] = *(const bf16x8*)&Wf[(16*w+col)*128 + ks*32 + quad*8];
    const float bv = b[16*w + col];
    __shared__ bf16 Alds[32][136];
    const int m_st = t >> 3, c_in = t & 7;
    for (int tb = blockIdx.x*32; tb < NN; tb += gridDim.x*32) {
        const float4* rx = (const float4*)&X[(long)(tb+m_st)*FF];
        #pragma unroll
        for (int it=0; it<4; ++it) {
            int cc = c_in + it*8;
            float4 v = rx[cc];
            bf16x4 bvv = {(bf16)v.x,(bf16)v.y,(bf16)v.z,(bf16)v.w};
            *(bf16x4*)&Alds[m_st][cc*4] = bvv;
        }
        __syncthreads();
        f32x4 acc[2] = {{0.f,0.f,0.f,0.f},{0.f,0.f,0.f,0.f}};
        #pragma unroll
        for (int ks=0; ks<4; ++ks)
            #pragma unroll
            for (int mt=0; mt<2; ++mt) {
                bf16x8 a = *(const bf16x8*)&Alds[mt*16+col][ks*32+quad*8];
                acc[mt] = __builtin_amdgcn_mfma_f32_16x16x32_bf16(a, B[ks], acc[mt], 0,0,0);
            }
        __syncthreads();
        #pragma unroll
        for (int mt=0; mt<2; ++mt)
            #pragma unroll
            for (int r=0; r<4; ++r) {
                long n = tb + mt*16 + quad*4 + r;
                float val = acc[mt][r] + bv;
                Y  [n*HH + 16*w+col] = val;
                Ybf[n*HH + 16*w+col] = (bf16)val;
            }
    }
}

// Fused con+GRU layer with a second MFMA stage applied to the GRU output
// tile (staged through LDS), eliminating the fp32 hA round-trip:
//   MODE 0: stage2 = W_lin1 (64x64) -> bf16 Obf   (replaces lin64 kernel)
//   MODE 1: stage2 = W_out  (16x64) + log_softmax -> f32 Of (replaces out kernel)
template<int MODE>
__global__ __launch_bounds__(256, 2) void layer_fused_kernel(
    const bf16* __restrict__ X1, const bf16* __restrict__ X2,
    const float* __restrict__ H, const bf16* __restrict__ Hbf,
    const bf16* __restrict__ Wg, const float* __restrict__ bg,
    const bf16* __restrict__ Wh, const float* __restrict__ bh,
    const bf16* __restrict__ Ws, const float* __restrict__ bs,
    bf16* __restrict__ Obf, float* __restrict__ Of)
{
    const int t    = threadIdx.x;
    const int w    = t >> 6;
    const int lane = t & 63;
    const int col  = lane & 15;
    const int quad = lane >> 4;

    bf16x8 Bg[3][4];
    bf16x8 Bh[3][2];
    float bgv[3], bhv[3];
    #pragma unroll
    for (int jt=0; jt<3; ++jt) {
        int J = jt*64 + 16*w + col;
        #pragma unroll
        for (int ks=0; ks<4; ++ks)
            Bg[jt][ks] = *(const bf16x8*)&Wg[J*128 + ks*32 + quad*8];
        #pragma unroll
        for (int ks=0; ks<2; ++ks)
            Bh[jt][ks] = *(const bf16x8*)&Wh[J*64 + ks*32 + quad*8];
        bgv[jt] = bg[J];
        bhv[jt] = bh[J];
    }

    // second-stage weight fragments + bias
    bf16x8 B2[2];
    float b2s;
    if constexpr (MODE == 0) {
        #pragma unroll
        for (int ks=0; ks<2; ++ks)
            B2[ks] = *(const bf16x8*)&Ws[(16*w+col)*64 + ks*32 + quad*8];
        b2s = bs[16*w + col];
    } else {
        #pragma unroll
        for (int ks=0; ks<2; ++ks)
            B2[ks] = *(const bf16x8*)&Ws[col*64 + ks*32 + quad*8];
        b2s = bs[col];
    }

    __shared__ bf16 Alds[32][200];
    __shared__ bf16 Glds[32][72];   // GRU output tile (bf16), stage-2 A operand

    const int m_st = t >> 3;
    const int c_in = t & 7;

    for (int tb = blockIdx.x*32; tb < NN; tb += gridDim.x*32) {
        {
            long n = tb + m_st;
            *(bf16x8*)&Alds[m_st][c_in*8]       = *(const bf16x8*)&X1[n*HH + c_in*8];
            *(bf16x8*)&Alds[m_st][64 + c_in*8]  = *(const bf16x8*)&X2[n*HH + c_in*8];
            *(bf16x8*)&Alds[m_st][128 + c_in*8] = *(const bf16x8*)&Hbf[n*HH + c_in*8];
        }
        __syncthreads();                                    // (A)

        f32x4 accg[2][3];
        f32x4 acch[2][3];
        #pragma unroll
        for (int mt=0; mt<2; ++mt)
            #pragma unroll
            for (int jt=0; jt<3; ++jt) {
                accg[mt][jt] = (f32x4){0.f,0.f,0.f,0.f};
                acch[mt][jt] = (f32x4){0.f,0.f,0.f,0.f};
            }

        #pragma unroll
        for (int ks=0; ks<4; ++ks) {
            #pragma unroll
            for (int mt=0; mt<2; ++mt) {
                bf16x8 a = *(const bf16x8*)&Alds[mt*16 + col][ks*32 + quad*8];
                #pragma unroll
                for (int jt=0; jt<3; ++jt)
                    accg[mt][jt] = __builtin_amdgcn_mfma_f32_16x16x32_bf16(
                        a, Bg[jt][ks], accg[mt][jt], 0, 0, 0);
            }
        }
        #pragma unroll
        for (int ks=0; ks<2; ++ks) {
            #pragma unroll
            for (int mt=0; mt<2; ++mt) {
                bf16x8 a = *(const bf16x8*)&Alds[mt*16 + col][128 + ks*32 + quad*8];
                #pragma unroll
                for (int jt=0; jt<3; ++jt)
                    acch[mt][jt] = __builtin_amdgcn_mfma_f32_16x16x32_bf16(
                        a, Bh[jt][ks], acch[mt][jt], 0, 0, 0);
            }
        }

        // GRU epilogue -> Glds (bf16 tile, rows = tile rows, cols = 64 feats)
        const int c = 16*w + col;
        #pragma unroll
        for (int mt=0; mt<2; ++mt) {
            #pragma unroll
            for (int r=0; r<4; ++r) {
                long n = tb + mt*16 + quad*4 + r;
                float gr = accg[mt][0][r] + bgv[0];
                float gz = accg[mt][1][r] + bgv[1];
                float gn = accg[mt][2][r] + bgv[2];
                float hr = acch[mt][0][r] + bhv[0];
                float hz = acch[mt][1][r] + bhv[1];
                float hn = acch[mt][2][r] + bhv[2];
                float rr = fsig(gr + hr);
                float zz = fsig(gz + hz);
                float nv = ftanh(gn + rr*hn);
                float hv = H[n*HH + c];
                Glds[mt*16 + quad*4 + r][c] = (bf16)((1.0f - zz)*nv + zz*hv);
            }
        }
        __syncthreads();                                    // (B)

        // ---- stage 2
        if constexpr (MODE == 0) {
            f32x4 acc2[2] = {{0.f,0.f,0.f,0.f},{0.f,0.f,0.f,0.f}};
            #pragma unroll
            for (int ks=0; ks<2; ++ks)
                #pragma unroll
                for (int mt=0; mt<2; ++mt) {
                    bf16x8 a = *(const bf16x8*)&Glds[mt*16+col][ks*32+quad*8];
                    acc2[mt] = __builtin_amdgcn_mfma_f32_16x16x32_bf16(a, B2[ks], acc2[mt], 0,0,0);
                }
            #pragma unroll
            for (int mt=0; mt<2; ++mt)
                #pragma unroll
                for (int r=0; r<4; ++r)
                    Obf[(long)(tb+mt*16+quad*4+r)*HH + 16*w+col] = (bf16)(acc2[mt][r] + b2s);
        } else {
            if (w < 2) {   // 32 rows = 2 waves x 16-row M tiles; C = 16 cols
                f32x4 acc2 = {0.f,0.f,0.f,0.f};
                #pragma unroll
                for (int ks=0; ks<2; ++ks) {
                    bf16x8 a = *(const bf16x8*)&Glds[w*16+col][ks*32+quad*8];
                    acc2 = __builtin_amdgcn_mfma_f32_16x16x32_bf16(a, B2[ks], acc2, 0,0,0);
                }
                #pragma unroll
                for (int r=0; r<4; ++r) {
                    long n = tb + w*16 + quad*4 + r;
                    float val = acc2[r] + b2s;
                    float m = val;
                    #pragma unroll
                    for (int off=8; off>0; off>>=1) m = fmaxf(m, __shfl_xor(m, off, 16));
                    float ex = __expf(val - m);
                    float ssum = ex;
                    #pragma unroll
                    for (int off=8; off>0; off>>=1) ssum += __shfl_xor(ssum, off, 16);
                    Of[n*CC + col] = val - m - __logf(ssum);
                }
            }
        }
        // next iteration's Alds writes are fenced from this iteration's main
        // MFMA reads by (B); next Glds writes are fenced from this stage-2's
        // reads by the next iteration's (A).
    }
}

extern "C" void kernel_launch(void* const* d_in, const int* in_sizes, int n_in,
                              void* d_out, int out_size, void* d_ws, size_t ws_size,
                              hipStream_t stream)
{
    const float* x       = (const float*)d_in[0];
    const int*   ei      = (const int*)  d_in[1];
    const float* ew      = (const float*)d_in[2];
    const int*   ei_re   = (const int*)  d_in[3];
    const float* ew_re   = (const float*)d_in[4];
    const float* W_first = (const float*)d_in[5];
    const float* b_first = (const float*)d_in[6];
    const float* W_con1  = (const float*)d_in[7];
    const float* b_con1  = (const float*)d_in[8];
    const float* W_con2  = (const float*)d_in[9];
    const float* b_con2  = (const float*)d_in[10];
    const float* W_lin1  = (const float*)d_in[11];
    const float* b_lin1  = (const float*)d_in[12];
    const float* W_out   = (const float*)d_in[13];
    const float* b_out   = (const float*)d_in[14];
    const float* W_ih    = (const float*)d_in[15];
    const float* W_hh    = (const float*)d_in[16];
    const float* b_ih    = (const float*)d_in[17];
    const float* b_hh    = (const float*)d_in[18];
    float* out = (float*)d_out;

    // ---- workspace layout
    float* h    = (float*)d_ws;                // [N*64] fp32 GRU state
    bf16*  x1b  = (bf16*)(h + (long)NN*HH);    // [N*64]
    bf16*  x2b  = x1b + (long)NN*HH;           // [N*64]
    bf16*  hbf  = x2b + (long)NN*HH;           // [N*64]
    bf16*  hAbf = hbf + (long)NN*HH;           // [N*64]
    float* b1 = (float*)(hAbf + (long)NN*HH);  // [192]
    float* b2 = b1 + 192;                      // [192]
    bf16*  W1bf = (bf16*)(b2 + 192);           // [192*128]
    bf16*  W2bf = W1bf + 192*128;
    bf16*  Whbf = W2bf + 192*128;
    bf16*  Wfbf = Whbf + 192*64;
    bf16*  Wlbf = Wfbf + 64*128;
    bf16*  Wobf = Wlbf + 64*64;
    uint2* edata = (uint2*)(Wobf + 16*64);     // [2E + 16] 8B records, dst-sorted
    int*   rp     = (int*)(edata + 2*EE + 16); // [NSEG+1]
    int*   bkcnt  = rp + NSEG + 1;             // [NBUK]
    int*   bkbase = bkcnt + NBUK;              // [NBUK+1]
    int*   bkcur  = bkbase + NBUK + 1;         // [NBUK]
    int*   tmp_d = (int*)x1b;                  // [2E] 8 MB (alias; dead until fillB done)
    uint2* tmp_p = (uint2*)h;                  // [2E] 16 MB (alias; h written after build)

    // 0) weights in bf16 (+ fp32 biases)
    precomp_kernel<<<(192*128 + 192 + 192*64 + 64*128 + 64*64 + 16*64 + 255)/256, 256, 0, stream>>>(
        W_ih, b_ih, W_con1, b_con1, W_con2, b_con2, W_hh, W_first, W_lin1, W_out,
        W1bf, b1, W2bf, b2, Whbf, Wfbf, Wlbf, Wobf);

    // 1) CSR build: bucket-count -> parallel 98-scan -> 2-phase sort
    hipMemsetAsync(bkcnt, 0, (size_t)NBUK*sizeof(int), stream);
    bucket_count_kernel<<<P1BLK, 256, 0, stream>>>(ei, ei_re, bkcnt);
    bucket_scan_kernel<<<1, 128, 0, stream>>>(bkcnt, bkbase, bkcur, rp);
    fillA_kernel<<<P1BLK, 256, 0, stream>>>(ei, ew, ei_re, ew_re, bkcur, tmp_d, tmp_p);
    fillB_kernel<<<NBUK, 1024, 0, stream>>>(bkbase, tmp_d, tmp_p, edata, rp);

    // 2) h = x @ W_first^T + b_first   (MFMA; fp32 + bf16 outputs)
    lin_first_mfma_kernel<<<1024, 256, 0, stream>>>(x, Wfbf, b_first, h, hbf);

    // 3) layer-1 propagation (quarter-wave, 4-deep, decode-free records)
    csr_prop_kernel<<<(NSEG + 3)/4, 256, 0, stream>>>(hbf, rp, edata, x1b, x2b);

    // 4) fused con1 + GRU + lin1 -> hAbf   (MFMA)
    layer_fused_kernel<0><<<1024, 256, 0, stream>>>(x1b, x2b, h, hbf, W1bf, b1, Whbf, b_hh,
                                                    Wlbf, b_lin1, hAbf, nullptr);

    // 5) layer-2 propagation
    csr_prop_kernel<<<(NSEG + 3)/4, 256, 0, stream>>>(hAbf, rp, edata, x1b, x2b);

    // 6) fused con2 + GRU + W_out + log_softmax -> out   (MFMA)
    layer_fused_kernel<1><<<1024, 256, 0, stream>>>(x1b, x2b, h, hbf, W2bf, b2, Whbf, b_hh,
                                                    Wobf, b_out, nullptr, out);
}

// Round 6
// 380.465 us; speedup vs baseline: 1.0867x; 1.0867x over previous
//
#include <hip/hip_runtime.h>

#define NN 100000
#define FF 128
#define HH 64
#define CC 16
#define EE 1000000
#define NSEG (2*NN)                 // segments: [0,NN) = fwd, [NN,2NN) = rev
#define BSH 11                      // bucket = d >> 11 (2048 dsts/bucket)
#define BKD  (1 << BSH)
#define NBUK ((NSEG + BKD - 1) / BKD)   // 98
#define EPB 4096                    // edges per fillA/bucket_count block
#define P1BLK ((2*EE + EPB - 1) / EPB)  // 489
#define PRE_TOT (192*128 + 192 + 192*64 + 64*128 + 64*64 + 16*64)  // 50368
#define PRE_BLK ((PRE_TOT + 255)/256)   // 197
#define LIN_TILES ((NN + 31)/32)        // 3125
#define LINB ((LIN_TILES + 3)/4)        // 782

typedef __bf16 bf16;
typedef __attribute__((ext_vector_type(8))) __bf16 bf16x8;
typedef __attribute__((ext_vector_type(4))) __bf16 bf16x4;
typedef __attribute__((ext_vector_type(4))) float f32x4;
typedef __attribute__((ext_vector_type(2))) float f32x2;

__device__ __forceinline__ float fsig(float t)  { return 1.0f/(1.0f+__expf(-t)); }
__device__ __forceinline__ float ftanh(float t) { return 1.0f - 2.0f/(__expf(2.0f*t)+1.0f); }

// pack (src, w>=0) into 4 B: src(17 bits) << 15 | bf16(w) sans sign (15 bits)
__device__ __forceinline__ unsigned pack_sw(int s, float w) {
    unsigned short u = __builtin_bit_cast(unsigned short, (bf16)w);
    return ((unsigned)s << 15) | (u & 0x7FFFu);
}

// ---- precomp body (combined weights in bf16 etc.), called per flat idx
__device__ __forceinline__ void precomp_body(int idx,
                               const float* __restrict__ W_ih, const float* __restrict__ b_ih,
                               const float* __restrict__ Wc1,  const float* __restrict__ bc1,
                               const float* __restrict__ Wc2,  const float* __restrict__ bc2,
                               const float* __restrict__ W_hh, const float* __restrict__ W_first,
                               const float* __restrict__ W_lin1, const float* __restrict__ W_out,
                               bf16* __restrict__ W1bf, float* __restrict__ b1,
                               bf16* __restrict__ W2bf, float* __restrict__ b2,
                               bf16* __restrict__ Whbf, bf16* __restrict__ Wfbf,
                               bf16* __restrict__ Wlbf, bf16* __restrict__ Wobf)
{
    const int t0 = 192*128;          // W1/W2
    const int t1 = t0 + 192;         // b1/b2
    const int t2 = t1 + 192*64;      // Whbf
    const int t3 = t2 + 64*128;      // Wfbf
    const int t4 = t3 + 64*64;       // Wlbf
    const int t5 = t4 + 16*64;       // Wobf
    if (idx < t0) {
        int j = idx >> 7, k = idx & 127;
        float s1 = 0.f, s2 = 0.f;
        for (int m=0; m<64; ++m) {
            float wih = W_ih[j*64+m];
            s1 += wih * Wc1[m*128+k];
            s2 += wih * Wc2[m*128+k];
        }
        W1bf[idx] = (bf16)s1; W2bf[idx] = (bf16)s2;
    } else if (idx < t1) {
        int j = idx - t0;
        float s1 = b_ih[j], s2 = b_ih[j];
        for (int m=0; m<64; ++m) {
            float wih = W_ih[j*64+m];
            s1 += wih * bc1[m];
            s2 += wih * bc2[m];
        }
        b1[j] = s1; b2[j] = s2;
    } else if (idx < t2) {
        int i = idx - t1;  Whbf[i] = (bf16)W_hh[i];
    } else if (idx < t3) {
        int i = idx - t2;  Wfbf[i] = (bf16)W_first[i];
    } else if (idx < t4) {
        int i = idx - t3;  Wlbf[i] = (bf16)W_lin1[i];
    } else if (idx < t5) {
        int i = idx - t4;  Wobf[i] = (bf16)W_out[i];
    }
}

// ===== merged: bucket_count (blocks 0..P1BLK) + precomp (rest) =====
__global__ __launch_bounds__(256) void count_precomp_kernel(
    const int* __restrict__ ei, const int* __restrict__ ei_re, int* __restrict__ bkcnt,
    const float* __restrict__ W_ih, const float* __restrict__ b_ih,
    const float* __restrict__ Wc1,  const float* __restrict__ bc1,
    const float* __restrict__ Wc2,  const float* __restrict__ bc2,
    const float* __restrict__ W_hh, const float* __restrict__ W_first,
    const float* __restrict__ W_lin1, const float* __restrict__ W_out,
    bf16* __restrict__ W1bf, float* __restrict__ b1,
    bf16* __restrict__ W2bf, float* __restrict__ b2,
    bf16* __restrict__ Whbf, bf16* __restrict__ Wfbf,
    bf16* __restrict__ Wlbf, bf16* __restrict__ Wobf)
{
    __shared__ int hist[NBUK];
    const int t = threadIdx.x;
    if (blockIdx.x < P1BLK) {
        for (int i=t; i<NBUK; i+=256) hist[i] = 0;
        __syncthreads();
        const long e0 = (long)blockIdx.x * EPB;
        #pragma unroll
        for (int it=0; it<16; ++it) {
            long e = e0 + it*256 + t;
            int d = -1;
            if (e < EE)        d = ei[EE + e];
            else if (e < 2*EE) d = NN + ei_re[EE + (e - EE)];
            if (d >= 0) atomicAdd(&hist[d >> BSH], 1);
        }
        __syncthreads();
        for (int i=t; i<NBUK; i+=256) if (hist[i]) atomicAdd(&bkcnt[i], hist[i]);
    } else {
        int idx = (blockIdx.x - P1BLK)*256 + t;
        precomp_body(idx, W_ih, b_ih, Wc1, bc1, Wc2, bc2, W_hh, W_first, W_lin1, W_out,
                     W1bf, b1, W2bf, b2, Whbf, Wfbf, Wlbf, Wobf);
    }
}

// parallel 128-thread scan of the 98 bucket counts
__global__ void bucket_scan_kernel(const int* __restrict__ bkcnt,
                                   int* __restrict__ bkbase, int* __restrict__ bkcur,
                                   int* __restrict__ rp)
{
    __shared__ int sc[128];
    const int t = threadIdx.x;      // 128 threads
    int v = (t < NBUK) ? bkcnt[t] : 0;
    sc[t] = v;
    __syncthreads();
    #pragma unroll
    for (int off=1; off<128; off<<=1) {
        int x = (t>=off) ? sc[t-off] : 0;
        __syncthreads();
        sc[t] += x;
        __syncthreads();
    }
    int excl = sc[t] - v;
    if (t < NBUK) { bkbase[t] = excl; bkcur[t] = excl; }
    if (t == NBUK-1) bkbase[NBUK] = sc[t];   // = 2E
    if (t == 0) rp[NSEG] = 2*EE;
}

__global__ __launch_bounds__(256) void fillA_kernel(const int* __restrict__ ei,
                                                    const float* __restrict__ ew,
                                                    const int* __restrict__ ei_re,
                                                    const float* __restrict__ ew_re,
                                                    int* __restrict__ bkcur,
                                                    int* __restrict__ tmp_d,
                                                    unsigned* __restrict__ tmp_p)
{
    __shared__ int hist[NBUK];
    __shared__ int base[NBUK];
    const int t = threadIdx.x;
    for (int i=t; i<NBUK; i+=256) hist[i] = 0;
    __syncthreads();
    const long e0 = (long)blockIdx.x * EPB;
    int pr[16];
    #pragma unroll
    for (int it=0; it<16; ++it) {
        long e = e0 + it*256 + t;
        int d = -1;
        if (e < EE)        d = ei[EE + e];
        else if (e < 2*EE) d = NN + ei_re[EE + (e - EE)];
        if (d >= 0) {
            int b = d >> BSH;
            int r = atomicAdd(&hist[b], 1);
            pr[it] = (b << 16) | r;
        } else pr[it] = -1;
    }
    __syncthreads();
    for (int i=t; i<NBUK; i+=256) base[i] = atomicAdd(&bkcur[i], hist[i]);
    __syncthreads();
    #pragma unroll
    for (int it=0; it<16; ++it) {
        if (pr[it] < 0) continue;
        long e = e0 + it*256 + t;
        int d, s; float w;
        if (e < EE) { d = ei[EE+e]; s = ei[e]; w = ew[e]; }
        else { long j = e - EE; d = NN + ei_re[EE+j]; s = ei_re[j]; w = ew_re[j]; }
        int pos = base[pr[it] >> 16] + (pr[it] & 0xFFFF);
        tmp_d[pos] = d;
        tmp_p[pos] = pack_sw(s, w);
    }
}

// ===== merged: fillB (blocks 0..NBUK) + lin_first (blocks NBUK..NBUK+LINB) =====
// fillB reads tmp_d/tmp_p (aliased to x1b/x2b); lin writes h/hbf — disjoint.
__global__ __launch_bounds__(1024) void fillB_lin_kernel(
    const int* __restrict__ bkbase,
    const int* __restrict__ tmp_d, const unsigned* __restrict__ tmp_p,
    unsigned* __restrict__ edata, int* __restrict__ rp,
    const float* __restrict__ X, const bf16* __restrict__ Wf,
    const float* __restrict__ bfirst, float* __restrict__ Y, bf16* __restrict__ Ybf)
{
    __shared__ __align__(16) char smem[4*32*136*2];   // 34816 B (lin) >= 12288 B (fillB)
    const int t = threadIdx.x;
    if (blockIdx.x < NBUK) {
        int* cntL  = (int*)smem;                 // [BKD]
        int* scanL = (int*)(smem + BKD*4);       // [1024]
        const int b  = blockIdx.x;
        const int d0 = b << BSH;
        const int dn = min(BKD, NSEG - d0);
        const int p0 = bkbase[b];
        const int p1 = bkbase[b+1];
        for (int i=t; i<BKD; i+=1024) cntL[i] = 0;
        __syncthreads();
        for (int pos = p0 + t; pos < p1; pos += 1024)
            atomicAdd(&cntL[tmp_d[pos] - d0], 1);
        __syncthreads();
        int a0 = cntL[2*t], a1 = cntL[2*t+1];
        int ps = a0 + a1;
        scanL[t] = ps;
        __syncthreads();
        #pragma unroll
        for (int off=1; off<1024; off<<=1) {
            int x = (t>=off) ? scanL[t-off] : 0;
            __syncthreads();
            scanL[t] += x;
            __syncthreads();
        }
        int g0 = p0 + scanL[t] - ps;
        int g1 = g0 + a0;
        if (2*t   < dn) rp[d0 + 2*t]   = g0;
        if (2*t+1 < dn) rp[d0 + 2*t+1] = g1;
        cntL[2*t]   = g0;
        cntL[2*t+1] = g1;
        __syncthreads();
        for (int pos = p0 + t; pos < p1; pos += 1024) {
            int d = tmp_d[pos];
            int p = atomicAdd(&cntL[d - d0], 1);
            edata[p] = tmp_p[pos];
        }
    } else {
        // 4 independent 256-thread lin_first tile-groups per block
        const int lb   = blockIdx.x - NBUK;
        const int sub  = t >> 8;            // 0..3
        const int tt   = t & 255;
        const int tile = lb*4 + sub;
        const bool valid = tile < LIN_TILES;
        const int tb = tile * 32;
        const int w = tt >> 6, lane = tt & 63, col = lane & 15, quad = lane >> 4;
        bf16* Alds = (bf16*)smem + sub*(32*136);    // [32][136]
        bf16x8 B[4];
        #pragma unroll
        for (int ks=0; ks<4; ++ks)
            B[ks] = *(const bf16x8*)&Wf[(16*w+col)*128 + ks*32 + quad*8];
        const float bv = bfirst[16*w + col];
        const int m_st = tt >> 3, c_in = tt & 7;
        if (valid) {
            const float4* rx = (const float4*)&X[(long)(tb+m_st)*FF];
            #pragma unroll
            for (int it=0; it<4; ++it) {
                int cc = c_in + it*8;
                float4 v = rx[cc];
                bf16x4 bvv = {(bf16)v.x,(bf16)v.y,(bf16)v.z,(bf16)v.w};
                *(bf16x4*)&Alds[m_st*136 + cc*4] = bvv;
            }
        }
        __syncthreads();
        f32x4 acc[2] = {{0.f,0.f,0.f,0.f},{0.f,0.f,0.f,0.f}};
        #pragma unroll
        for (int ks=0; ks<4; ++ks)
            #pragma unroll
            for (int mt=0; mt<2; ++mt) {
                bf16x8 a = *(const bf16x8*)&Alds[(mt*16+col)*136 + ks*32+quad*8];
                acc[mt] = __builtin_amdgcn_mfma_f32_16x16x32_bf16(a, B[ks], acc[mt], 0,0,0);
            }
        if (valid) {
            #pragma unroll
            for (int mt=0; mt<2; ++mt)
                #pragma unroll
                for (int r=0; r<4; ++r) {
                    long n = tb + mt*16 + quad*4 + r;
                    float val = acc[mt][r] + bv;
                    Y  [n*HH + 16*w+col] = val;
                    Ybf[n*HH + 16*w+col] = (bf16)val;
                }
        }
    }
}

// Quarter-wave gather segment-sum (R10/R4 proven 56.4us — UNCHANGED):
//  - edata addressed by one byte-cursor + compile-time offsets
//  - overread past e1 (<=60B) lands in rp[] which follows edata; w masked 0
//  - invalid slots gather row 0 (globally hot in L1)
//  - bf16->f32 via <<16 / &0xFFFF0000 pairs, float2 accum (v_pk_fma_f32)
//  - 4 independent X gathers in flight (R11/R12/R13: deviating regressed)
__global__ __launch_bounds__(256) void csr_prop_kernel(const bf16* __restrict__ X,
    const int* __restrict__ rp, const unsigned* __restrict__ edata,
    bf16* __restrict__ x1, bf16* __restrict__ x2)
{
    int s = blockIdx.x*4 + (threadIdx.x>>6);
    if (s >= NSEG) return;
    const int lane = threadIdx.x & 63;
    const int q  = lane >> 4;      // edge slot 0..3
    const int fl = lane & 15;      // feature group: 4fl .. 4fl+3
    const unsigned foff = 8u*(unsigned)fl;
    const int e0 = rp[s], e1 = rp[s+1];
    const char* Xb = (const char*)X;
    const char* Eb = (const char*)edata;

    f32x2 acc01 = {0.f, 0.f}, acc23 = {0.f, 0.f};
    int eq = e0 + q;
    unsigned eqb = 4u*(unsigned)eq;
    for (int base = e0; base < e1; base += 16, eq += 16, eqb += 64u) {
        const int rem = e1 - eq;
        #pragma unroll
        for (int j=0; j<4; ++j) {
            unsigned p = *(const unsigned*)(Eb + (eqb + 16u*(unsigned)j));
            const bool v = (4*j < rem);
            float w = v ? __uint_as_float((p & 0x7FFFu) << 16) : 0.f;
            unsigned voff = v ? (((p >> 8) & 0xFFFFFF80u) | foff) : foff;
            uint2 d = *(const uint2*)(Xb + voff);
            f32x2 lo = { __uint_as_float(d.x << 16), __uint_as_float(d.x & 0xFFFF0000u) };
            f32x2 hi = { __uint_as_float(d.y << 16), __uint_as_float(d.y & 0xFFFF0000u) };
            f32x2 w2 = { w, w };
            acc01 += w2 * lo;
            acc23 += w2 * hi;
        }
    }
    float a0 = acc01.x, a1 = acc01.y, a2 = acc23.x, a3 = acc23.y;
    // reduce across the 4 quarters (lanes with equal fl)
    a0 += __shfl_xor(a0, 32); a0 += __shfl_xor(a0, 16);
    a1 += __shfl_xor(a1, 32); a1 += __shfl_xor(a1, 16);
    a2 += __shfl_xor(a2, 32); a2 += __shfl_xor(a2, 16);
    a3 += __shfl_xor(a3, 32); a3 += __shfl_xor(a3, 16);
    if (q == 0) {
        bf16* o = (s < NN) ? &x1[(long)s*HH] : &x2[(long)(s-NN)*HH];
        bf16x4 ov = {(bf16)a0, (bf16)a1, (bf16)a2, (bf16)a3};
        *(bf16x4*)&o[4*fl] = ov;
    }
}

// Fused con+GRU layer with a second MFMA stage applied to the GRU output
// tile (staged through LDS), eliminating the fp32 hA round-trip:
//   MODE 0: stage2 = W_lin1 (64x64) -> bf16 Obf
//   MODE 1: stage2 = W_out  (16x64) + log_softmax -> f32 Of
template<int MODE>
__global__ __launch_bounds__(256, 2) void layer_fused_kernel(
    const bf16* __restrict__ X1, const bf16* __restrict__ X2,
    const float* __restrict__ H, const bf16* __restrict__ Hbf,
    const bf16* __restrict__ Wg, const float* __restrict__ bg,
    const bf16* __restrict__ Wh, const float* __restrict__ bh,
    const bf16* __restrict__ Ws, const float* __restrict__ bs,
    bf16* __restrict__ Obf, float* __restrict__ Of)
{
    const int t    = threadIdx.x;
    const int w    = t >> 6;
    const int lane = t & 63;
    const int col  = lane & 15;
    const int quad = lane >> 4;

    bf16x8 Bg[3][4];
    bf16x8 Bh[3][2];
    float bgv[3], bhv[3];
    #pragma unroll
    for (int jt=0; jt<3; ++jt) {
        int J = jt*64 + 16*w + col;
        #pragma unroll
        for (int ks=0; ks<4; ++ks)
            Bg[jt][ks] = *(const bf16x8*)&Wg[J*128 + ks*32 + quad*8];
        #pragma unroll
        for (int ks=0; ks<2; ++ks)
            Bh[jt][ks] = *(const bf16x8*)&Wh[J*64 + ks*32 + quad*8];
        bgv[jt] = bg[J];
        bhv[jt] = bh[J];
    }

    bf16x8 B2[2];
    float b2s;
    if constexpr (MODE == 0) {
        #pragma unroll
        for (int ks=0; ks<2; ++ks)
            B2[ks] = *(const bf16x8*)&Ws[(16*w+col)*64 + ks*32 + quad*8];
        b2s = bs[16*w + col];
    } else {
        #pragma unroll
        for (int ks=0; ks<2; ++ks)
            B2[ks] = *(const bf16x8*)&Ws[col*64 + ks*32 + quad*8];
        b2s = bs[col];
    }

    __shared__ bf16 Alds[32][200];
    __shared__ bf16 Glds[32][72];   // GRU output tile (bf16), stage-2 A operand

    const int m_st = t >> 3;
    const int c_in = t & 7;

    for (int tb = blockIdx.x*32; tb < NN; tb += gridDim.x*32) {
        {
            long n = tb + m_st;
            *(bf16x8*)&Alds[m_st][c_in*8]       = *(const bf16x8*)&X1[n*HH + c_in*8];
            *(bf16x8*)&Alds[m_st][64 + c_in*8]  = *(const bf16x8*)&X2[n*HH + c_in*8];
            *(bf16x8*)&Alds[m_st][128 + c_in*8] = *(const bf16x8*)&Hbf[n*HH + c_in*8];
        }
        __syncthreads();                                    // (A)

        f32x4 accg[2][3];
        f32x4 acch[2][3];
        #pragma unroll
        for (int mt=0; mt<2; ++mt)
            #pragma unroll
            for (int jt=0; jt<3; ++jt) {
                accg[mt][jt] = (f32x4){0.f,0.f,0.f,0.f};
                acch[mt][jt] = (f32x4){0.f,0.f,0.f,0.f};
            }

        #pragma unroll
        for (int ks=0; ks<4; ++ks) {
            #pragma unroll
            for (int mt=0; mt<2; ++mt) {
                bf16x8 a = *(const bf16x8*)&Alds[mt*16 + col][ks*32 + quad*8];
                #pragma unroll
                for (int jt=0; jt<3; ++jt)
                    accg[mt][jt] = __builtin_amdgcn_mfma_f32_16x16x32_bf16(
                        a, Bg[jt][ks], accg[mt][jt], 0, 0, 0);
            }
        }
        #pragma unroll
        for (int ks=0; ks<2; ++ks) {
            #pragma unroll
            for (int mt=0; mt<2; ++mt) {
                bf16x8 a = *(const bf16x8*)&Alds[mt*16 + col][128 + ks*32 + quad*8];
                #pragma unroll
                for (int jt=0; jt<3; ++jt)
                    acch[mt][jt] = __builtin_amdgcn_mfma_f32_16x16x32_bf16(
                        a, Bh[jt][ks], acch[mt][jt], 0, 0, 0);
            }
        }

        // GRU epilogue -> Glds (bf16 tile, rows = tile rows, cols = 64 feats)
        const int c = 16*w + col;
        #pragma unroll
        for (int mt=0; mt<2; ++mt) {
            #pragma unroll
            for (int r=0; r<4; ++r) {
                long n = tb + mt*16 + quad*4 + r;
                float gr = accg[mt][0][r] + bgv[0];
                float gz = accg[mt][1][r] + bgv[1];
                float gn = accg[mt][2][r] + bgv[2];
                float hr = acch[mt][0][r] + bhv[0];
                float hz = acch[mt][1][r] + bhv[1];
                float hn = acch[mt][2][r] + bhv[2];
                float rr = fsig(gr + hr);
                float zz = fsig(gz + hz);
                float nv = ftanh(gn + rr*hn);
                float hv = H[n*HH + c];
                Glds[mt*16 + quad*4 + r][c] = (bf16)((1.0f - zz)*nv + zz*hv);
            }
        }
        __syncthreads();                                    // (B)

        // ---- stage 2
        if constexpr (MODE == 0) {
            f32x4 acc2[2] = {{0.f,0.f,0.f,0.f},{0.f,0.f,0.f,0.f}};
            #pragma unroll
            for (int ks=0; ks<2; ++ks)
                #pragma unroll
                for (int mt=0; mt<2; ++mt) {
                    bf16x8 a = *(const bf16x8*)&Glds[mt*16+col][ks*32+quad*8];
                    acc2[mt] = __builtin_amdgcn_mfma_f32_16x16x32_bf16(a, B2[ks], acc2[mt], 0,0,0);
                }
            #pragma unroll
            for (int mt=0; mt<2; ++mt)
                #pragma unroll
                for (int r=0; r<4; ++r)
                    Obf[(long)(tb+mt*16+quad*4+r)*HH + 16*w+col] = (bf16)(acc2[mt][r] + b2s);
        } else {
            if (w < 2) {   // 32 rows = 2 waves x 16-row M tiles; C = 16 cols
                f32x4 acc2 = {0.f,0.f,0.f,0.f};
                #pragma unroll
                for (int ks=0; ks<2; ++ks) {
                    bf16x8 a = *(const bf16x8*)&Glds[w*16+col][ks*32+quad*8];
                    acc2 = __builtin_amdgcn_mfma_f32_16x16x32_bf16(a, B2[ks], acc2, 0,0,0);
                }
                #pragma unroll
                for (int r=0; r<4; ++r) {
                    long n = tb + w*16 + quad*4 + r;
                    float val = acc2[r] + b2s;
                    float m = val;
                    #pragma unroll
                    for (int off=8; off>0; off>>=1) m = fmaxf(m, __shfl_xor(m, off, 16));
                    float ex = __expf(val - m);
                    float ssum = ex;
                    #pragma unroll
                    for (int off=8; off>0; off>>=1) ssum += __shfl_xor(ssum, off, 16);
                    Of[n*CC + col] = val - m - __logf(ssum);
                }
            }
        }
    }
}

extern "C" void kernel_launch(void* const* d_in, const int* in_sizes, int n_in,
                              void* d_out, int out_size, void* d_ws, size_t ws_size,
                              hipStream_t stream)
{
    const float* x       = (const float*)d_in[0];
    const int*   ei      = (const int*)  d_in[1];
    const float* ew      = (const float*)d_in[2];
    const int*   ei_re   = (const int*)  d_in[3];
    const float* ew_re   = (const float*)d_in[4];
    const float* W_first = (const float*)d_in[5];
    const float* b_first = (const float*)d_in[6];
    const float* W_con1  = (const float*)d_in[7];
    const float* b_con1  = (const float*)d_in[8];
    const float* W_con2  = (const float*)d_in[9];
    const float* b_con2  = (const float*)d_in[10];
    const float* W_lin1  = (const float*)d_in[11];
    const float* b_lin1  = (const float*)d_in[12];
    const float* W_out   = (const float*)d_in[13];
    const float* b_out   = (const float*)d_in[14];
    const float* W_ih    = (const float*)d_in[15];
    const float* W_hh    = (const float*)d_in[16];
    const float* b_ih    = (const float*)d_in[17];
    const float* b_hh    = (const float*)d_in[18];
    float* out = (float*)d_out;

    // ---- workspace layout (edata BEFORE rp so csr_prop's <=60B edata
    //      overread lands in the live rp array, not past ws)
    float* h    = (float*)d_ws;                // [N*64] fp32 GRU state
    bf16*  x1b  = (bf16*)(h + (long)NN*HH);    // [N*64]
    bf16*  x2b  = x1b + (long)NN*HH;           // [N*64]
    bf16*  hbf  = x2b + (long)NN*HH;           // [N*64]
    bf16*  hAbf = hbf + (long)NN*HH;           // [N*64]
    float* b1 = (float*)(hAbf + (long)NN*HH);  // [192]
    float* b2 = b1 + 192;                      // [192]
    bf16*  W1bf = (bf16*)(b2 + 192);           // [192*128]
    bf16*  W2bf = W1bf + 192*128;
    bf16*  Whbf = W2bf + 192*128;
    bf16*  Wfbf = Whbf + 192*64;
    bf16*  Wlbf = Wfbf + 64*128;
    bf16*  Wobf = Wlbf + 64*64;
    unsigned* edata = (unsigned*)(Wobf + 16*64); // [2E] packed (src,w), dst-sorted
    int*   rp     = (int*)(edata + 2*EE);      // [NSEG+1]  (doubles as edata overread pad)
    int*   bkcnt  = rp + NSEG + 1;             // [NBUK]
    int*   bkbase = bkcnt + NBUK;              // [NBUK+1]
    int*   bkcur  = bkbase + NBUK + 1;         // [NBUK]
    int*      tmp_d = (int*)x1b;               // [2E] 8 MB (aliases, dead until fillB done)
    unsigned* tmp_p = (unsigned*)x2b;          // [2E] 8 MB

    // 1) bucket-count + weight precomp (merged, independent block ranges)
    hipMemsetAsync(bkcnt, 0, (size_t)NBUK*sizeof(int), stream);
    count_precomp_kernel<<<P1BLK + PRE_BLK, 256, 0, stream>>>(
        ei, ei_re, bkcnt,
        W_ih, b_ih, W_con1, b_con1, W_con2, b_con2, W_hh, W_first, W_lin1, W_out,
        W1bf, b1, W2bf, b2, Whbf, Wfbf, Wlbf, Wobf);

    // 2) parallel 98-scan
    bucket_scan_kernel<<<1, 128, 0, stream>>>(bkcnt, bkbase, bkcur, rp);

    // 3) fillA (2-phase sort, phase 1)
    fillA_kernel<<<P1BLK, 256, 0, stream>>>(ei, ew, ei_re, ew_re, bkcur, tmp_d, tmp_p);

    // 4) fillB + lin_first (merged: sort phase 2 overlaps the W_first MFMA GEMM)
    fillB_lin_kernel<<<NBUK + LINB, 1024, 0, stream>>>(
        bkbase, tmp_d, tmp_p, edata, rp, x, Wfbf, b_first, h, hbf);

    // 5) layer-1 propagation (quarter-wave, 4-deep, proven structure)
    csr_prop_kernel<<<(NSEG + 3)/4, 256, 0, stream>>>(hbf, rp, edata, x1b, x2b);

    // 6) fused con1 + GRU + lin1 -> hAbf   (MFMA)
    layer_fused_kernel<0><<<1024, 256, 0, stream>>>(x1b, x2b, h, hbf, W1bf, b1, Whbf, b_hh,
                                                    Wlbf, b_lin1, hAbf, nullptr);

    // 7) layer-2 propagation
    csr_prop_kernel<<<(NSEG + 3)/4, 256, 0, stream>>>(hAbf, rp, edata, x1b, x2b);

    // 8) fused con2 + GRU + W_out + log_softmax -> out   (MFMA)
    layer_fused_kernel<1><<<1024, 256, 0, stream>>>(x1b, x2b, h, hbf, W2bf, b2, Whbf, b_hh,
                                                    Wobf, b_out, nullptr, out);
}

// Round 7
// 370.081 us; speedup vs baseline: 1.1171x; 1.0281x over previous
//
#include <hip/hip_runtime.h>

#define NN 100000
#define FF 128
#define HH 64
#define CC 16
#define EE 1000000
#define NSEG (2*NN)                 // segments: [0,NN) = fwd, [NN,2NN) = rev
#define BSH 11                      // bucket = d >> 11 (2048 dsts/bucket)
#define BKD  (1 << BSH)
#define NBUK ((NSEG + BKD - 1) / BKD)   // 98
#define EPB 4096                    // edges per fillA/bucket_count block
#define P1BLK ((2*EE + EPB - 1) / EPB)  // 489
#define PRE_TOT (192*128 + 192 + 192*64 + 64*128 + 64*64 + 16*64)  // 50368
#define PRE_BLK ((PRE_TOT + 255)/256)   // 197
#define LIN_TILES ((NN + 31)/32)        // 3125
#define LINB ((LIN_TILES + 3)/4)        // 782
#define CSRB 2048                       // persistent csr_prop grid

typedef __bf16 bf16;
typedef __attribute__((ext_vector_type(8))) __bf16 bf16x8;
typedef __attribute__((ext_vector_type(4))) __bf16 bf16x4;
typedef __attribute__((ext_vector_type(4))) float f32x4;
typedef __attribute__((ext_vector_type(2))) float f32x2;

__device__ __forceinline__ float fsig(float t)  { return 1.0f/(1.0f+__expf(-t)); }
__device__ __forceinline__ float ftanh(float t) { return 1.0f - 2.0f/(__expf(2.0f*t)+1.0f); }

// pack (src, w>=0) into 4 B: src(17 bits) << 15 | bf16(w) sans sign (15 bits)
__device__ __forceinline__ unsigned pack_sw(int s, float w) {
    unsigned short u = __builtin_bit_cast(unsigned short, (bf16)w);
    return ((unsigned)s << 15) | (u & 0x7FFFu);
}

// ---- precomp body (combined weights in bf16 etc.), called per flat idx
__device__ __forceinline__ void precomp_body(int idx,
                               const float* __restrict__ W_ih, const float* __restrict__ b_ih,
                               const float* __restrict__ Wc1,  const float* __restrict__ bc1,
                               const float* __restrict__ Wc2,  const float* __restrict__ bc2,
                               const float* __restrict__ W_hh, const float* __restrict__ W_first,
                               const float* __restrict__ W_lin1, const float* __restrict__ W_out,
                               bf16* __restrict__ W1bf, float* __restrict__ b1,
                               bf16* __restrict__ W2bf, float* __restrict__ b2,
                               bf16* __restrict__ Whbf, bf16* __restrict__ Wfbf,
                               bf16* __restrict__ Wlbf, bf16* __restrict__ Wobf)
{
    const int t0 = 192*128;          // W1/W2
    const int t1 = t0 + 192;         // b1/b2
    const int t2 = t1 + 192*64;      // Whbf
    const int t3 = t2 + 64*128;      // Wfbf
    const int t4 = t3 + 64*64;       // Wlbf
    const int t5 = t4 + 16*64;       // Wobf
    if (idx < t0) {
        int j = idx >> 7, k = idx & 127;
        float s1 = 0.f, s2 = 0.f;
        for (int m=0; m<64; ++m) {
            float wih = W_ih[j*64+m];
            s1 += wih * Wc1[m*128+k];
            s2 += wih * Wc2[m*128+k];
        }
        W1bf[idx] = (bf16)s1; W2bf[idx] = (bf16)s2;
    } else if (idx < t1) {
        int j = idx - t0;
        float s1 = b_ih[j], s2 = b_ih[j];
        for (int m=0; m<64; ++m) {
            float wih = W_ih[j*64+m];
            s1 += wih * bc1[m];
            s2 += wih * bc2[m];
        }
        b1[j] = s1; b2[j] = s2;
    } else if (idx < t2) {
        int i = idx - t1;  Whbf[i] = (bf16)W_hh[i];
    } else if (idx < t3) {
        int i = idx - t2;  Wfbf[i] = (bf16)W_first[i];
    } else if (idx < t4) {
        int i = idx - t3;  Wlbf[i] = (bf16)W_lin1[i];
    } else if (idx < t5) {
        int i = idx - t4;  Wobf[i] = (bf16)W_out[i];
    }
}

// ===== merged: bucket_count (blocks 0..P1BLK) + precomp (rest) =====
__global__ __launch_bounds__(256) void count_precomp_kernel(
    const int* __restrict__ ei, const int* __restrict__ ei_re, int* __restrict__ bkcnt,
    const float* __restrict__ W_ih, const float* __restrict__ b_ih,
    const float* __restrict__ Wc1,  const float* __restrict__ bc1,
    const float* __restrict__ Wc2,  const float* __restrict__ bc2,
    const float* __restrict__ W_hh, const float* __restrict__ W_first,
    const float* __restrict__ W_lin1, const float* __restrict__ W_out,
    bf16* __restrict__ W1bf, float* __restrict__ b1,
    bf16* __restrict__ W2bf, float* __restrict__ b2,
    bf16* __restrict__ Whbf, bf16* __restrict__ Wfbf,
    bf16* __restrict__ Wlbf, bf16* __restrict__ Wobf)
{
    __shared__ int hist[NBUK];
    const int t = threadIdx.x;
    if (blockIdx.x < P1BLK) {
        for (int i=t; i<NBUK; i+=256) hist[i] = 0;
        __syncthreads();
        const long e0 = (long)blockIdx.x * EPB;
        #pragma unroll
        for (int it=0; it<16; ++it) {
            long e = e0 + it*256 + t;
            int d = -1;
            if (e < EE)        d = ei[EE + e];
            else if (e < 2*EE) d = NN + ei_re[EE + (e - EE)];
            if (d >= 0) atomicAdd(&hist[d >> BSH], 1);
        }
        __syncthreads();
        for (int i=t; i<NBUK; i+=256) if (hist[i]) atomicAdd(&bkcnt[i], hist[i]);
    } else {
        int idx = (blockIdx.x - P1BLK)*256 + t;
        precomp_body(idx, W_ih, b_ih, Wc1, bc1, Wc2, bc2, W_hh, W_first, W_lin1, W_out,
                     W1bf, b1, W2bf, b2, Whbf, Wfbf, Wlbf, Wobf);
    }
}

// fillA: per-block histogram + in-block 128-thread scan of global bucket
// counts (bucket_scan kernel eliminated; bkcur pre-zeroed by memset)
__global__ __launch_bounds__(256) void fillA_kernel(const int* __restrict__ ei,
                                                    const float* __restrict__ ew,
                                                    const int* __restrict__ ei_re,
                                                    const float* __restrict__ ew_re,
                                                    const int* __restrict__ bkcnt,
                                                    int* __restrict__ bkcur,
                                                    int* __restrict__ tmp_d,
                                                    unsigned* __restrict__ tmp_p)
{
    __shared__ int hist[NBUK];
    __shared__ int base[NBUK];
    __shared__ int sc[128];
    const int t = threadIdx.x;
    for (int i=t; i<NBUK; i+=256) hist[i] = 0;
    int v = 0;
    if (t < 128) { v = (t < NBUK) ? bkcnt[t] : 0; sc[t] = v; }
    __syncthreads();
    const long e0 = (long)blockIdx.x * EPB;
    int pr[16];
    #pragma unroll
    for (int it=0; it<16; ++it) {
        long e = e0 + it*256 + t;
        int d = -1;
        if (e < EE)        d = ei[EE + e];
        else if (e < 2*EE) d = NN + ei_re[EE + (e - EE)];
        if (d >= 0) {
            int b = d >> BSH;
            int r = atomicAdd(&hist[b], 1);
            pr[it] = (b << 16) | r;
        } else pr[it] = -1;
    }
    __syncthreads();
    #pragma unroll
    for (int off=1; off<128; off<<=1) {
        int x = 0;
        if (t >= off && t < 128) x = sc[t-off];
        __syncthreads();
        if (t < 128) sc[t] += x;
        __syncthreads();
    }
    if (t < 128 && t < NBUK) base[t] = sc[t] - v;   // exclusive global prefix
    __syncthreads();
    for (int i=t; i<NBUK; i+=256) base[i] += atomicAdd(&bkcur[i], hist[i]);
    __syncthreads();
    #pragma unroll
    for (int it=0; it<16; ++it) {
        if (pr[it] < 0) continue;
        long e = e0 + it*256 + t;
        int d, s; float w;
        if (e < EE) { d = ei[EE+e]; s = ei[e]; w = ew[e]; }
        else { long j = e - EE; d = NN + ei_re[EE+j]; s = ei_re[j]; w = ew_re[j]; }
        int pos = base[pr[it] >> 16] + (pr[it] & 0xFFFF);
        tmp_d[pos] = d;
        tmp_p[pos] = pack_sw(s, w);
    }
}

// ===== merged: fillB (blocks 0..NBUK) + lin_first (blocks NBUK..NBUK+LINB) =====
// fillB reads tmp_d/tmp_p (aliased to x1b/x2b); lin writes h/hbf — disjoint.
__global__ __launch_bounds__(1024) void fillB_lin_kernel(
    const int* __restrict__ bkcnt,
    const int* __restrict__ tmp_d, const unsigned* __restrict__ tmp_p,
    unsigned* __restrict__ edata, int* __restrict__ rp,
    const float* __restrict__ X, const bf16* __restrict__ Wf,
    const float* __restrict__ bfirst, float* __restrict__ Y, bf16* __restrict__ Ybf)
{
    __shared__ __align__(16) char smem[4*32*136*2];   // 34816 B (lin) >= 12800 B (fillB)
    const int t = threadIdx.x;
    if (blockIdx.x < NBUK) {
        int* cntL  = (int*)smem;                       // [BKD]
        int* scanL = (int*)(smem + BKD*4);             // [1024]
        int* sc98  = (int*)(smem + BKD*4 + 4096);      // [128]
        const int b  = blockIdx.x;
        const int d0 = b << BSH;
        const int dn = min(BKD, NSEG - d0);
        if (b == 0 && t == 0) rp[NSEG] = 2*EE;
        if (t < 128) sc98[t] = (t < NBUK) ? bkcnt[t] : 0;
        for (int i=t; i<BKD; i+=1024) cntL[i] = 0;
        __syncthreads();
        #pragma unroll
        for (int off=1; off<128; off<<=1) {
            int x = 0;
            if (t >= off && t < 128) x = sc98[t-off];
            __syncthreads();
            if (t < 128) sc98[t] += x;
            __syncthreads();
        }
        const int p0 = (b == 0) ? 0 : sc98[b-1];
        const int p1 = sc98[b];
        for (int pos = p0 + t; pos < p1; pos += 1024)
            atomicAdd(&cntL[tmp_d[pos] - d0], 1);
        __syncthreads();
        int a0 = cntL[2*t], a1 = cntL[2*t+1];
        int ps = a0 + a1;
        scanL[t] = ps;
        __syncthreads();
        #pragma unroll
        for (int off=1; off<1024; off<<=1) {
            int x = (t>=off) ? scanL[t-off] : 0;
            __syncthreads();
            scanL[t] += x;
            __syncthreads();
        }
        int g0 = p0 + scanL[t] - ps;
        int g1 = g0 + a0;
        if (2*t   < dn) rp[d0 + 2*t]   = g0;
        if (2*t+1 < dn) rp[d0 + 2*t+1] = g1;
        cntL[2*t]   = g0;
        cntL[2*t+1] = g1;
        __syncthreads();
        for (int pos = p0 + t; pos < p1; pos += 1024) {
            int d = tmp_d[pos];
            int p = atomicAdd(&cntL[d - d0], 1);
            edata[p] = tmp_p[pos];
        }
    } else {
        // 4 independent 256-thread lin_first tile-groups per block
        const int lb   = blockIdx.x - NBUK;
        const int sub  = t >> 8;            // 0..3
        const int tt   = t & 255;
        const int tile = lb*4 + sub;
        const bool valid = tile < LIN_TILES;
        const int tb = tile * 32;
        const int w = tt >> 6, lane = tt & 63, col = lane & 15, quad = lane >> 4;
        bf16* Alds = (bf16*)smem + sub*(32*136);    // [32][136]
        bf16x8 B[4];
        #pragma unroll
        for (int ks=0; ks<4; ++ks)
            B[ks] = *(const bf16x8*)&Wf[(16*w+col)*128 + ks*32 + quad*8];
        const float bv = bfirst[16*w + col];
        const int m_st = tt >> 3, c_in = tt & 7;
        if (valid) {
            const float4* rx = (const float4*)&X[(long)(tb+m_st)*FF];
            #pragma unroll
            for (int it=0; it<4; ++it) {
                int cc = c_in + it*8;
                float4 v = rx[cc];
                bf16x4 bvv = {(bf16)v.x,(bf16)v.y,(bf16)v.z,(bf16)v.w};
                *(bf16x4*)&Alds[m_st*136 + cc*4] = bvv;
            }
        }
        __syncthreads();
        f32x4 acc[2] = {{0.f,0.f,0.f,0.f},{0.f,0.f,0.f,0.f}};
        #pragma unroll
        for (int ks=0; ks<4; ++ks)
            #pragma unroll
            for (int mt=0; mt<2; ++mt) {
                bf16x8 a = *(const bf16x8*)&Alds[(mt*16+col)*136 + ks*32+quad*8];
                acc[mt] = __builtin_amdgcn_mfma_f32_16x16x32_bf16(a, B[ks], acc[mt], 0,0,0);
            }
        if (valid) {
            #pragma unroll
            for (int mt=0; mt<2; ++mt)
                #pragma unroll
                for (int r=0; r<4; ++r) {
                    long n = tb + mt*16 + quad*4 + r;
                    float val = acc[mt][r] + bv;
                    Y  [n*HH + 16*w+col] = val;
                    Ybf[n*HH + 16*w+col] = (bf16)val;
                }
        }
    }
}

// Quarter-wave gather segment-sum (R10/R4 proven inner loop — UNCHANGED),
// now with a PERSISTENT grid (2048 blocks x 4 waves = 32 waves/CU, grid-
// stride over segment quads) to eliminate tiny-block churn/drain.
__global__ __launch_bounds__(256) void csr_prop_kernel(const bf16* __restrict__ X,
    const int* __restrict__ rp, const unsigned* __restrict__ edata,
    bf16* __restrict__ x1, bf16* __restrict__ x2)
{
    const int lane = threadIdx.x & 63;
    const int q  = lane >> 4;      // edge slot 0..3
    const int fl = lane & 15;      // feature group: 4fl .. 4fl+3
    const unsigned foff = 8u*(unsigned)fl;
    const char* Xb = (const char*)X;
    const char* Eb = (const char*)edata;

    for (int s = blockIdx.x*4 + (threadIdx.x>>6); s < NSEG; s += gridDim.x*4) {
        const int e0 = rp[s], e1 = rp[s+1];
        f32x2 acc01 = {0.f, 0.f}, acc23 = {0.f, 0.f};
        int eq = e0 + q;
        unsigned eqb = 4u*(unsigned)eq;
        for (int base = e0; base < e1; base += 16, eq += 16, eqb += 64u) {
            const int rem = e1 - eq;
            #pragma unroll
            for (int j=0; j<4; ++j) {
                unsigned p = *(const unsigned*)(Eb + (eqb + 16u*(unsigned)j));
                const bool v = (4*j < rem);
                float w = v ? __uint_as_float((p & 0x7FFFu) << 16) : 0.f;
                unsigned voff = v ? (((p >> 8) & 0xFFFFFF80u) | foff) : foff;
                uint2 d = *(const uint2*)(Xb + voff);
                f32x2 lo = { __uint_as_float(d.x << 16), __uint_as_float(d.x & 0xFFFF0000u) };
                f32x2 hi = { __uint_as_float(d.y << 16), __uint_as_float(d.y & 0xFFFF0000u) };
                f32x2 w2 = { w, w };
                acc01 += w2 * lo;
                acc23 += w2 * hi;
            }
        }
        float a0 = acc01.x, a1 = acc01.y, a2 = acc23.x, a3 = acc23.y;
        // reduce across the 4 quarters (lanes with equal fl)
        a0 += __shfl_xor(a0, 32); a0 += __shfl_xor(a0, 16);
        a1 += __shfl_xor(a1, 32); a1 += __shfl_xor(a1, 16);
        a2 += __shfl_xor(a2, 32); a2 += __shfl_xor(a2, 16);
        a3 += __shfl_xor(a3, 32); a3 += __shfl_xor(a3, 16);
        if (q == 0) {
            bf16* o = (s < NN) ? &x1[(long)s*HH] : &x2[(long)(s-NN)*HH];
            bf16x4 ov = {(bf16)a0, (bf16)a1, (bf16)a2, (bf16)a3};
            *(bf16x4*)&o[4*fl] = ov;
        }
    }
}

// Fused con+GRU layer with a second MFMA stage applied to the GRU output
// tile (staged through LDS), eliminating the fp32 hA round-trip:
//   MODE 0: stage2 = W_lin1 (64x64) -> bf16 Obf
//   MODE 1: stage2 = W_out  (16x64) + log_softmax -> f32 Of
// H is read ONCE as fp32 float4 (coalesced): converted in-register to the
// bf16 MFMA fragment (bit-identical to the old Hbf path) AND parked fp32 in
// LDS (row pad 66 -> quads land 8 banks apart, conflict-free) so the
// epilogue's hv comes from LDS instead of a scattered global re-read.
template<int MODE>
__global__ __launch_bounds__(256, 2) void layer_fused_kernel(
    const bf16* __restrict__ X1, const bf16* __restrict__ X2,
    const float* __restrict__ H,
    const bf16* __restrict__ Wg, const float* __restrict__ bg,
    const bf16* __restrict__ Wh, const float* __restrict__ bh,
    const bf16* __restrict__ Ws, const float* __restrict__ bs,
    bf16* __restrict__ Obf, float* __restrict__ Of)
{
    const int t    = threadIdx.x;
    const int w    = t >> 6;
    const int lane = t & 63;
    const int col  = lane & 15;
    const int quad = lane >> 4;

    bf16x8 Bg[3][4];
    bf16x8 Bh[3][2];
    float bgv[3], bhv[3];
    #pragma unroll
    for (int jt=0; jt<3; ++jt) {
        int J = jt*64 + 16*w + col;
        #pragma unroll
        for (int ks=0; ks<4; ++ks)
            Bg[jt][ks] = *(const bf16x8*)&Wg[J*128 + ks*32 + quad*8];
        #pragma unroll
        for (int ks=0; ks<2; ++ks)
            Bh[jt][ks] = *(const bf16x8*)&Wh[J*64 + ks*32 + quad*8];
        bgv[jt] = bg[J];
        bhv[jt] = bh[J];
    }

    bf16x8 B2[2];
    float b2s;
    if constexpr (MODE == 0) {
        #pragma unroll
        for (int ks=0; ks<2; ++ks)
            B2[ks] = *(const bf16x8*)&Ws[(16*w+col)*64 + ks*32 + quad*8];
        b2s = bs[16*w + col];
    } else {
        #pragma unroll
        for (int ks=0; ks<2; ++ks)
            B2[ks] = *(const bf16x8*)&Ws[col*64 + ks*32 + quad*8];
        b2s = bs[col];
    }

    __shared__ bf16  Alds[32][200];
    __shared__ bf16  Glds[32][72];   // GRU output tile (bf16), stage-2 A operand
    __shared__ float Hlds[32][66];   // fp32 H tile for the epilogue

    const int m_st = t >> 3;
    const int c_in = t & 7;

    for (int tb = blockIdx.x*32; tb < NN; tb += gridDim.x*32) {
        {
            long n = tb + m_st;
            *(bf16x8*)&Alds[m_st][c_in*8]      = *(const bf16x8*)&X1[n*HH + c_in*8];
            *(bf16x8*)&Alds[m_st][64 + c_in*8] = *(const bf16x8*)&X2[n*HH + c_in*8];
            const float4* rh = (const float4*)&H[n*HH];
            float4 a = rh[c_in*2], b4 = rh[c_in*2+1];
            bf16x8 hb = {(bf16)a.x,(bf16)a.y,(bf16)a.z,(bf16)a.w,
                         (bf16)b4.x,(bf16)b4.y,(bf16)b4.z,(bf16)b4.w};
            *(bf16x8*)&Alds[m_st][128 + c_in*8] = hb;
            *(float4*)&Hlds[m_st][c_in*8]     = a;
            *(float4*)&Hlds[m_st][c_in*8 + 4] = b4;
        }
        __syncthreads();                                    // (A)

        f32x4 accg[2][3];
        f32x4 acch[2][3];
        #pragma unroll
        for (int mt=0; mt<2; ++mt)
            #pragma unroll
            for (int jt=0; jt<3; ++jt) {
                accg[mt][jt] = (f32x4){0.f,0.f,0.f,0.f};
                acch[mt][jt] = (f32x4){0.f,0.f,0.f,0.f};
            }

        #pragma unroll
        for (int ks=0; ks<4; ++ks) {
            #pragma unroll
            for (int mt=0; mt<2; ++mt) {
                bf16x8 a = *(const bf16x8*)&Alds[mt*16 + col][ks*32 + quad*8];
                #pragma unroll
                for (int jt=0; jt<3; ++jt)
                    accg[mt][jt] = __builtin_amdgcn_mfma_f32_16x16x32_bf16(
                        a, Bg[jt][ks], accg[mt][jt], 0, 0, 0);
            }
        }
        #pragma unroll
        for (int ks=0; ks<2; ++ks) {
            #pragma unroll
            for (int mt=0; mt<2; ++mt) {
                bf16x8 a = *(const bf16x8*)&Alds[mt*16 + col][128 + ks*32 + quad*8];
                #pragma unroll
                for (int jt=0; jt<3; ++jt)
                    acch[mt][jt] = __builtin_amdgcn_mfma_f32_16x16x32_bf16(
                        a, Bh[jt][ks], acch[mt][jt], 0, 0, 0);
            }
        }

        // GRU epilogue -> Glds (bf16 tile, rows = tile rows, cols = 64 feats)
        const int c = 16*w + col;
        #pragma unroll
        for (int mt=0; mt<2; ++mt) {
            #pragma unroll
            for (int r=0; r<4; ++r) {
                float gr = accg[mt][0][r] + bgv[0];
                float gz = accg[mt][1][r] + bgv[1];
                float gn = accg[mt][2][r] + bgv[2];
                float hr = acch[mt][0][r] + bhv[0];
                float hz = acch[mt][1][r] + bhv[1];
                float hn = acch[mt][2][r] + bhv[2];
                float rr = fsig(gr + hr);
                float zz = fsig(gz + hz);
                float nv = ftanh(gn + rr*hn);
                float hv = Hlds[mt*16 + quad*4 + r][c];
                Glds[mt*16 + quad*4 + r][c] = (bf16)((1.0f - zz)*nv + zz*hv);
            }
        }
        __syncthreads();                                    // (B)

        // ---- stage 2
        if constexpr (MODE == 0) {
            f32x4 acc2[2] = {{0.f,0.f,0.f,0.f},{0.f,0.f,0.f,0.f}};
            #pragma unroll
            for (int ks=0; ks<2; ++ks)
                #pragma unroll
                for (int mt=0; mt<2; ++mt) {
                    bf16x8 a = *(const bf16x8*)&Glds[mt*16+col][ks*32+quad*8];
                    acc2[mt] = __builtin_amdgcn_mfma_f32_16x16x32_bf16(a, B2[ks], acc2[mt], 0,0,0);
                }
            #pragma unroll
            for (int mt=0; mt<2; ++mt)
                #pragma unroll
                for (int r=0; r<4; ++r)
                    Obf[(long)(tb+mt*16+quad*4+r)*HH + 16*w+col] = (bf16)(acc2[mt][r] + b2s);
        } else {
            if (w < 2) {   // 32 rows = 2 waves x 16-row M tiles; C = 16 cols
                f32x4 acc2 = {0.f,0.f,0.f,0.f};
                #pragma unroll
                for (int ks=0; ks<2; ++ks) {
                    bf16x8 a = *(const bf16x8*)&Glds[w*16+col][ks*32+quad*8];
                    acc2 = __builtin_amdgcn_mfma_f32_16x16x32_bf16(a, B2[ks], acc2, 0,0,0);
                }
                #pragma unroll
                for (int r=0; r<4; ++r) {
                    long n = tb + w*16 + quad*4 + r;
                    float val = acc2[r] + b2s;
                    float m = val;
                    #pragma unroll
                    for (int off=8; off>0; off>>=1) m = fmaxf(m, __shfl_xor(m, off, 16));
                    float ex = __expf(val - m);
                    float ssum = ex;
                    #pragma unroll
                    for (int off=8; off>0; off>>=1) ssum += __shfl_xor(ssum, off, 16);
                    Of[n*CC + col] = val - m - __logf(ssum);
                }
            }
        }
    }
}

extern "C" void kernel_launch(void* const* d_in, const int* in_sizes, int n_in,
                              void* d_out, int out_size, void* d_ws, size_t ws_size,
                              hipStream_t stream)
{
    const float* x       = (const float*)d_in[0];
    const int*   ei      = (const int*)  d_in[1];
    const float* ew      = (const float*)d_in[2];
    const int*   ei_re   = (const int*)  d_in[3];
    const float* ew_re   = (const float*)d_in[4];
    const float* W_first = (const float*)d_in[5];
    const float* b_first = (const float*)d_in[6];
    const float* W_con1  = (const float*)d_in[7];
    const float* b_con1  = (const float*)d_in[8];
    const float* W_con2  = (const float*)d_in[9];
    const float* b_con2  = (const float*)d_in[10];
    const float* W_lin1  = (const float*)d_in[11];
    const float* b_lin1  = (const float*)d_in[12];
    const float* W_out   = (const float*)d_in[13];
    const float* b_out   = (const float*)d_in[14];
    const float* W_ih    = (const float*)d_in[15];
    const float* W_hh    = (const float*)d_in[16];
    const float* b_ih    = (const float*)d_in[17];
    const float* b_hh    = (const float*)d_in[18];
    float* out = (float*)d_out;

    // ---- workspace layout (edata BEFORE rp so csr_prop's <=60B edata
    //      overread lands in the live rp array, not past ws)
    float* h    = (float*)d_ws;                // [N*64] fp32 GRU state
    bf16*  x1b  = (bf16*)(h + (long)NN*HH);    // [N*64]
    bf16*  x2b  = x1b + (long)NN*HH;           // [N*64]
    bf16*  hbf  = x2b + (long)NN*HH;           // [N*64]
    bf16*  hAbf = hbf + (long)NN*HH;           // [N*64]
    float* b1 = (float*)(hAbf + (long)NN*HH);  // [192]
    float* b2 = b1 + 192;                      // [192]
    bf16*  W1bf = (bf16*)(b2 + 192);           // [192*128]
    bf16*  W2bf = W1bf + 192*128;
    bf16*  Whbf = W2bf + 192*128;
    bf16*  Wfbf = Whbf + 192*64;
    bf16*  Wlbf = Wfbf + 64*128;
    bf16*  Wobf = Wlbf + 64*64;
    unsigned* edata = (unsigned*)(Wobf + 16*64); // [2E] packed (src,w), dst-sorted
    int*   rp     = (int*)(edata + 2*EE);      // [NSEG+1]  (doubles as edata overread pad)
    int*   bkcnt  = rp + NSEG + 1;             // [NBUK]
    int*   bkcur  = bkcnt + NBUK;              // [NBUK] (adjacent: one memset covers both)
    int*      tmp_d = (int*)x1b;               // [2E] 8 MB (aliases, dead until fillB done)
    unsigned* tmp_p = (unsigned*)x2b;          // [2E] 8 MB

    // 1) bucket-count + weight precomp (merged, independent block ranges)
    hipMemsetAsync(bkcnt, 0, (size_t)(2*NBUK)*sizeof(int), stream);
    count_precomp_kernel<<<P1BLK + PRE_BLK, 256, 0, stream>>>(
        ei, ei_re, bkcnt,
        W_ih, b_ih, W_con1, b_con1, W_con2, b_con2, W_hh, W_first, W_lin1, W_out,
        W1bf, b1, W2bf, b2, Whbf, Wfbf, Wlbf, Wobf);

    // 2) fillA (2-phase sort, phase 1; in-block global-prefix scan)
    fillA_kernel<<<P1BLK, 256, 0, stream>>>(ei, ew, ei_re, ew_re, bkcnt, bkcur, tmp_d, tmp_p);

    // 3) fillB + lin_first (merged: sort phase 2 overlaps the W_first MFMA GEMM)
    fillB_lin_kernel<<<NBUK + LINB, 1024, 0, stream>>>(
        bkcnt, tmp_d, tmp_p, edata, rp, x, Wfbf, b_first, h, hbf);

    // 4) layer-1 propagation (persistent grid, proven inner loop)
    csr_prop_kernel<<<CSRB, 256, 0, stream>>>(hbf, rp, edata, x1b, x2b);

    // 5) fused con1 + GRU + lin1 -> hAbf   (MFMA)
    layer_fused_kernel<0><<<1024, 256, 0, stream>>>(x1b, x2b, h, W1bf, b1, Whbf, b_hh,
                                                    Wlbf, b_lin1, hAbf, nullptr);

    // 6) layer-2 propagation
    csr_prop_kernel<<<CSRB, 256, 0, stream>>>(hAbf, rp, edata, x1b, x2b);

    // 7) fused con2 + GRU + W_out + log_softmax -> out   (MFMA)
    layer_fused_kernel<1><<<1024, 256, 0, stream>>>(x1b, x2b, h, W2bf, b2, Whbf, b_hh,
                                                    Wobf, b_out, nullptr, out);
}

// Round 8
// 369.163 us; speedup vs baseline: 1.1199x; 1.0025x over previous
//
#include <hip/hip_runtime.h>

#define NN 100000
#define FF 128
#define HH 64
#define CC 16
#define EE 1000000
#define NSEG (2*NN)                 // segments: [0,NN) = fwd, [NN,2NN) = rev
#define BSH 11                      // bucket = d >> 11 (2048 dsts/bucket)
#define BKD  (1 << BSH)
#define NBUK ((NSEG + BKD - 1) / BKD)   // 98
#define EPB 4096                    // edges per fillA/bucket_count block
#define P1BLK ((2*EE + EPB - 1) / EPB)  // 489
#define PRE_TOT (192*128 + 192 + 192*64 + 64*128 + 64*64 + 16*64)  // 50368
#define PRE_BLK ((PRE_TOT + 255)/256)   // 197
#define LIN_TILES ((NN + 31)/32)        // 3125
#define LINB ((LIN_TILES + 3)/4)        // 782
#define CSRB 2048                       // persistent csr_prop grid

typedef __bf16 bf16;
typedef __attribute__((ext_vector_type(8))) __bf16 bf16x8;
typedef __attribute__((ext_vector_type(4))) __bf16 bf16x4;
typedef __attribute__((ext_vector_type(4))) float f32x4;
typedef __attribute__((ext_vector_type(2))) float f32x2;

__device__ __forceinline__ float fsig(float t)  { return 1.0f/(1.0f+__expf(-t)); }
__device__ __forceinline__ float ftanh(float t) { return 1.0f - 2.0f/(__expf(2.0f*t)+1.0f); }

// pack (src, w>=0) into 4 B: src(17 bits) << 15 | bf16(w) sans sign (15 bits)
__device__ __forceinline__ unsigned pack_sw(int s, float w) {
    unsigned short u = __builtin_bit_cast(unsigned short, (bf16)w);
    return ((unsigned)s << 15) | (u & 0x7FFFu);
}

// ---- precomp body (combined weights in bf16 etc.), called per flat idx
__device__ __forceinline__ void precomp_body(int idx,
                               const float* __restrict__ W_ih, const float* __restrict__ b_ih,
                               const float* __restrict__ Wc1,  const float* __restrict__ bc1,
                               const float* __restrict__ Wc2,  const float* __restrict__ bc2,
                               const float* __restrict__ W_hh, const float* __restrict__ W_first,
                               const float* __restrict__ W_lin1, const float* __restrict__ W_out,
                               bf16* __restrict__ W1bf, float* __restrict__ b1,
                               bf16* __restrict__ W2bf, float* __restrict__ b2,
                               bf16* __restrict__ Whbf, bf16* __restrict__ Wfbf,
                               bf16* __restrict__ Wlbf, bf16* __restrict__ Wobf)
{
    const int t0 = 192*128;          // W1/W2
    const int t1 = t0 + 192;         // b1/b2
    const int t2 = t1 + 192*64;      // Whbf
    const int t3 = t2 + 64*128;      // Wfbf
    const int t4 = t3 + 64*64;       // Wlbf
    const int t5 = t4 + 16*64;       // Wobf
    if (idx < t0) {
        int j = idx >> 7, k = idx & 127;
        float s1 = 0.f, s2 = 0.f;
        for (int m=0; m<64; ++m) {
            float wih = W_ih[j*64+m];
            s1 += wih * Wc1[m*128+k];
            s2 += wih * Wc2[m*128+k];
        }
        W1bf[idx] = (bf16)s1; W2bf[idx] = (bf16)s2;
    } else if (idx < t1) {
        int j = idx - t0;
        float s1 = b_ih[j], s2 = b_ih[j];
        for (int m=0; m<64; ++m) {
            float wih = W_ih[j*64+m];
            s1 += wih * bc1[m];
            s2 += wih * bc2[m];
        }
        b1[j] = s1; b2[j] = s2;
    } else if (idx < t2) {
        int i = idx - t1;  Whbf[i] = (bf16)W_hh[i];
    } else if (idx < t3) {
        int i = idx - t2;  Wfbf[i] = (bf16)W_first[i];
    } else if (idx < t4) {
        int i = idx - t3;  Wlbf[i] = (bf16)W_lin1[i];
    } else if (idx < t5) {
        int i = idx - t4;  Wobf[i] = (bf16)W_out[i];
    }
}

// ===== merged: bucket_count (blocks 0..P1BLK) + precomp (rest) =====
__global__ __launch_bounds__(256) void count_precomp_kernel(
    const int* __restrict__ ei, const int* __restrict__ ei_re, int* __restrict__ bkcnt,
    const float* __restrict__ W_ih, const float* __restrict__ b_ih,
    const float* __restrict__ Wc1,  const float* __restrict__ bc1,
    const float* __restrict__ Wc2,  const float* __restrict__ bc2,
    const float* __restrict__ W_hh, const float* __restrict__ W_first,
    const float* __restrict__ W_lin1, const float* __restrict__ W_out,
    bf16* __restrict__ W1bf, float* __restrict__ b1,
    bf16* __restrict__ W2bf, float* __restrict__ b2,
    bf16* __restrict__ Whbf, bf16* __restrict__ Wfbf,
    bf16* __restrict__ Wlbf, bf16* __restrict__ Wobf)
{
    __shared__ int hist[NBUK];
    const int t = threadIdx.x;
    if (blockIdx.x < P1BLK) {
        for (int i=t; i<NBUK; i+=256) hist[i] = 0;
        __syncthreads();
        const long e0 = (long)blockIdx.x * EPB;
        #pragma unroll
        for (int it=0; it<16; ++it) {
            long e = e0 + it*256 + t;
            int d = -1;
            if (e < EE)        d = ei[EE + e];
            else if (e < 2*EE) d = NN + ei_re[EE + (e - EE)];
            if (d >= 0) atomicAdd(&hist[d >> BSH], 1);
        }
        __syncthreads();
        for (int i=t; i<NBUK; i+=256) if (hist[i]) atomicAdd(&bkcnt[i], hist[i]);
    } else {
        int idx = (blockIdx.x - P1BLK)*256 + t;
        precomp_body(idx, W_ih, b_ih, Wc1, bc1, Wc2, bc2, W_hh, W_first, W_lin1, W_out,
                     W1bf, b1, W2bf, b2, Whbf, Wfbf, Wlbf, Wobf);
    }
}

// fillA: per-block histogram + in-block 128-thread scan of global bucket
// counts (bucket_scan kernel eliminated; bkcur pre-zeroed by memset)
__global__ __launch_bounds__(256) void fillA_kernel(const int* __restrict__ ei,
                                                    const float* __restrict__ ew,
                                                    const int* __restrict__ ei_re,
                                                    const float* __restrict__ ew_re,
                                                    const int* __restrict__ bkcnt,
                                                    int* __restrict__ bkcur,
                                                    int* __restrict__ tmp_d,
                                                    unsigned* __restrict__ tmp_p)
{
    __shared__ int hist[NBUK];
    __shared__ int base[NBUK];
    __shared__ int sc[128];
    const int t = threadIdx.x;
    for (int i=t; i<NBUK; i+=256) hist[i] = 0;
    int v = 0;
    if (t < 128) { v = (t < NBUK) ? bkcnt[t] : 0; sc[t] = v; }
    __syncthreads();
    const long e0 = (long)blockIdx.x * EPB;
    int pr[16];
    #pragma unroll
    for (int it=0; it<16; ++it) {
        long e = e0 + it*256 + t;
        int d = -1;
        if (e < EE)        d = ei[EE + e];
        else if (e < 2*EE) d = NN + ei_re[EE + (e - EE)];
        if (d >= 0) {
            int b = d >> BSH;
            int r = atomicAdd(&hist[b], 1);
            pr[it] = (b << 16) | r;
        } else pr[it] = -1;
    }
    __syncthreads();
    #pragma unroll
    for (int off=1; off<128; off<<=1) {
        int x = 0;
        if (t >= off && t < 128) x = sc[t-off];
        __syncthreads();
        if (t < 128) sc[t] += x;
        __syncthreads();
    }
    if (t < 128 && t < NBUK) base[t] = sc[t] - v;   // exclusive global prefix
    __syncthreads();
    for (int i=t; i<NBUK; i+=256) base[i] += atomicAdd(&bkcur[i], hist[i]);
    __syncthreads();
    #pragma unroll
    for (int it=0; it<16; ++it) {
        if (pr[it] < 0) continue;
        long e = e0 + it*256 + t;
        int d, s; float w;
        if (e < EE) { d = ei[EE+e]; s = ei[e]; w = ew[e]; }
        else { long j = e - EE; d = NN + ei_re[EE+j]; s = ei_re[j]; w = ew_re[j]; }
        int pos = base[pr[it] >> 16] + (pr[it] & 0xFFFF);
        tmp_d[pos] = d;
        tmp_p[pos] = pack_sw(s, w);
    }
}

// ===== merged: fillB (blocks 0..NBUK) + lin_first (blocks NBUK..NBUK+LINB) =====
// fillB reads tmp_d/tmp_p (aliased to x1b/x2b); lin writes h/hbf — disjoint.
__global__ __launch_bounds__(1024) void fillB_lin_kernel(
    const int* __restrict__ bkcnt,
    const int* __restrict__ tmp_d, const unsigned* __restrict__ tmp_p,
    unsigned* __restrict__ edata, int* __restrict__ rp,
    const float* __restrict__ X, const bf16* __restrict__ Wf,
    const float* __restrict__ bfirst, float* __restrict__ Y, bf16* __restrict__ Ybf)
{
    __shared__ __align__(16) char smem[4*32*136*2];   // 34816 B (lin) >= 12800 B (fillB)
    const int t = threadIdx.x;
    if (blockIdx.x < NBUK) {
        int* cntL  = (int*)smem;                       // [BKD]
        int* scanL = (int*)(smem + BKD*4);             // [1024]
        int* sc98  = (int*)(smem + BKD*4 + 4096);      // [128]
        const int b  = blockIdx.x;
        const int d0 = b << BSH;
        const int dn = min(BKD, NSEG - d0);
        if (b == 0 && t == 0) rp[NSEG] = 2*EE;
        if (t < 128) sc98[t] = (t < NBUK) ? bkcnt[t] : 0;
        for (int i=t; i<BKD; i+=1024) cntL[i] = 0;
        __syncthreads();
        #pragma unroll
        for (int off=1; off<128; off<<=1) {
            int x = 0;
            if (t >= off && t < 128) x = sc98[t-off];
            __syncthreads();
            if (t < 128) sc98[t] += x;
            __syncthreads();
        }
        const int p0 = (b == 0) ? 0 : sc98[b-1];
        const int p1 = sc98[b];
        for (int pos = p0 + t; pos < p1; pos += 1024)
            atomicAdd(&cntL[tmp_d[pos] - d0], 1);
        __syncthreads();
        int a0 = cntL[2*t], a1 = cntL[2*t+1];
        int ps = a0 + a1;
        scanL[t] = ps;
        __syncthreads();
        #pragma unroll
        for (int off=1; off<1024; off<<=1) {
            int x = (t>=off) ? scanL[t-off] : 0;
            __syncthreads();
            scanL[t] += x;
            __syncthreads();
        }
        int g0 = p0 + scanL[t] - ps;
        int g1 = g0 + a0;
        if (2*t   < dn) rp[d0 + 2*t]   = g0;
        if (2*t+1 < dn) rp[d0 + 2*t+1] = g1;
        cntL[2*t]   = g0;
        cntL[2*t+1] = g1;
        __syncthreads();
        for (int pos = p0 + t; pos < p1; pos += 1024) {
            int d = tmp_d[pos];
            int p = atomicAdd(&cntL[d - d0], 1);
            edata[p] = tmp_p[pos];
        }
    } else {
        // 4 independent 256-thread lin_first tile-groups per block
        const int lb   = blockIdx.x - NBUK;
        const int sub  = t >> 8;            // 0..3
        const int tt   = t & 255;
        const int tile = lb*4 + sub;
        const bool valid = tile < LIN_TILES;
        const int tb = tile * 32;
        const int w = tt >> 6, lane = tt & 63, col = lane & 15, quad = lane >> 4;
        bf16* Alds = (bf16*)smem + sub*(32*136);    // [32][136]
        bf16x8 B[4];
        #pragma unroll
        for (int ks=0; ks<4; ++ks)
            B[ks] = *(const bf16x8*)&Wf[(16*w+col)*128 + ks*32 + quad*8];
        const float bv = bfirst[16*w + col];
        const int m_st = tt >> 3, c_in = tt & 7;
        if (valid) {
            const float4* rx = (const float4*)&X[(long)(tb+m_st)*FF];
            #pragma unroll
            for (int it=0; it<4; ++it) {
                int cc = c_in + it*8;
                float4 v = rx[cc];
                bf16x4 bvv = {(bf16)v.x,(bf16)v.y,(bf16)v.z,(bf16)v.w};
                *(bf16x4*)&Alds[m_st*136 + cc*4] = bvv;
            }
        }
        __syncthreads();
        f32x4 acc[2] = {{0.f,0.f,0.f,0.f},{0.f,0.f,0.f,0.f}};
        #pragma unroll
        for (int ks=0; ks<4; ++ks)
            #pragma unroll
            for (int mt=0; mt<2; ++mt) {
                bf16x8 a = *(const bf16x8*)&Alds[(mt*16+col)*136 + ks*32+quad*8];
                acc[mt] = __builtin_amdgcn_mfma_f32_16x16x32_bf16(a, B[ks], acc[mt], 0,0,0);
            }
        if (valid) {
            #pragma unroll
            for (int mt=0; mt<2; ++mt)
                #pragma unroll
                for (int r=0; r<4; ++r) {
                    long n = tb + mt*16 + quad*4 + r;
                    float val = acc[mt][r] + bv;
                    Y  [n*HH + 16*w+col] = val;
                    Ybf[n*HH + 16*w+col] = (bf16)val;
                }
        }
    }
}

// Quarter-wave gather segment-sum (R10/R4 proven inner loop — UNCHANGED),
// persistent grid (2048 blocks x 4 waves, grid-stride over segments).
__global__ __launch_bounds__(256) void csr_prop_kernel(const bf16* __restrict__ X,
    const int* __restrict__ rp, const unsigned* __restrict__ edata,
    bf16* __restrict__ x1, bf16* __restrict__ x2)
{
    const int lane = threadIdx.x & 63;
    const int q  = lane >> 4;      // edge slot 0..3
    const int fl = lane & 15;      // feature group: 4fl .. 4fl+3
    const unsigned foff = 8u*(unsigned)fl;
    const char* Xb = (const char*)X;
    const char* Eb = (const char*)edata;

    for (int s = blockIdx.x*4 + (threadIdx.x>>6); s < NSEG; s += gridDim.x*4) {
        const int e0 = rp[s], e1 = rp[s+1];
        f32x2 acc01 = {0.f, 0.f}, acc23 = {0.f, 0.f};
        int eq = e0 + q;
        unsigned eqb = 4u*(unsigned)eq;
        for (int base = e0; base < e1; base += 16, eq += 16, eqb += 64u) {
            const int rem = e1 - eq;
            #pragma unroll
            for (int j=0; j<4; ++j) {
                unsigned p = *(const unsigned*)(Eb + (eqb + 16u*(unsigned)j));
                const bool v = (4*j < rem);
                float w = v ? __uint_as_float((p & 0x7FFFu) << 16) : 0.f;
                unsigned voff = v ? (((p >> 8) & 0xFFFFFF80u) | foff) : foff;
                uint2 d = *(const uint2*)(Xb + voff);
                f32x2 lo = { __uint_as_float(d.x << 16), __uint_as_float(d.x & 0xFFFF0000u) };
                f32x2 hi = { __uint_as_float(d.y << 16), __uint_as_float(d.y & 0xFFFF0000u) };
                f32x2 w2 = { w, w };
                acc01 += w2 * lo;
                acc23 += w2 * hi;
            }
        }
        float a0 = acc01.x, a1 = acc01.y, a2 = acc23.x, a3 = acc23.y;
        // reduce across the 4 quarters (lanes with equal fl)
        a0 += __shfl_xor(a0, 32); a0 += __shfl_xor(a0, 16);
        a1 += __shfl_xor(a1, 32); a1 += __shfl_xor(a1, 16);
        a2 += __shfl_xor(a2, 32); a2 += __shfl_xor(a2, 16);
        a3 += __shfl_xor(a3, 32); a3 += __shfl_xor(a3, 16);
        if (q == 0) {
            bf16* o = (s < NN) ? &x1[(long)s*HH] : &x2[(long)(s-NN)*HH];
            bf16x4 ov = {(bf16)a0, (bf16)a1, (bf16)a2, (bf16)a3};
            *(bf16x4*)&o[4*fl] = ov;
        }
    }
}

// Fused con+GRU layer, second MFMA stage through Glds; fp32 hA eliminated.
//   MODE 0: stage2 = W_lin1 (64x64) -> bf16 Obf
//   MODE 1: stage2 = W_out  (16x64) + log_softmax -> f32 Of
// R8: T14 async-stage split — next tile's X1/X2/H are loaded into registers
// right after barrier (A), so HBM/L2 latency hides under stage-1 MFMA +
// GRU epilogue + stage-2. All Alds/Hlds reads complete before barrier (B);
// the register->LDS writes happen after (B) at the next loop top — the two
// existing barriers fence every hazard. Numerics bit-identical.
template<int MODE>
__global__ __launch_bounds__(256, 2) void layer_fused_kernel(
    const bf16* __restrict__ X1, const bf16* __restrict__ X2,
    const float* __restrict__ H,
    const bf16* __restrict__ Wg, const float* __restrict__ bg,
    const bf16* __restrict__ Wh, const float* __restrict__ bh,
    const bf16* __restrict__ Ws, const float* __restrict__ bs,
    bf16* __restrict__ Obf, float* __restrict__ Of)
{
    const int t    = threadIdx.x;
    const int w    = t >> 6;
    const int lane = t & 63;
    const int col  = lane & 15;
    const int quad = lane >> 4;

    bf16x8 Bg[3][4];
    bf16x8 Bh[3][2];
    float bgv[3], bhv[3];
    #pragma unroll
    for (int jt=0; jt<3; ++jt) {
        int J = jt*64 + 16*w + col;
        #pragma unroll
        for (int ks=0; ks<4; ++ks)
            Bg[jt][ks] = *(const bf16x8*)&Wg[J*128 + ks*32 + quad*8];
        #pragma unroll
        for (int ks=0; ks<2; ++ks)
            Bh[jt][ks] = *(const bf16x8*)&Wh[J*64 + ks*32 + quad*8];
        bgv[jt] = bg[J];
        bhv[jt] = bh[J];
    }

    bf16x8 B2[2];
    float b2s;
    if constexpr (MODE == 0) {
        #pragma unroll
        for (int ks=0; ks<2; ++ks)
            B2[ks] = *(const bf16x8*)&Ws[(16*w+col)*64 + ks*32 + quad*8];
        b2s = bs[16*w + col];
    } else {
        #pragma unroll
        for (int ks=0; ks<2; ++ks)
            B2[ks] = *(const bf16x8*)&Ws[col*64 + ks*32 + quad*8];
        b2s = bs[col];
    }

    __shared__ bf16  Alds[32][200];
    __shared__ bf16  Glds[32][72];   // GRU output tile (bf16), stage-2 A operand
    __shared__ float Hlds[32][66];   // fp32 H tile for the epilogue

    const int m_st = t >> 3;
    const int c_in = t & 7;

    // prefetch first tile into registers
    bf16x8 pX1, pX2;
    float4 pHa, pHb;
    {
        long n = (long)blockIdx.x*32 + m_st;
        pX1 = *(const bf16x8*)&X1[n*HH + c_in*8];
        pX2 = *(const bf16x8*)&X2[n*HH + c_in*8];
        const float4* rh = (const float4*)&H[n*HH];
        pHa = rh[c_in*2]; pHb = rh[c_in*2+1];
    }

    for (int tb = blockIdx.x*32; tb < NN; tb += gridDim.x*32) {
        {
            *(bf16x8*)&Alds[m_st][c_in*8]      = pX1;
            *(bf16x8*)&Alds[m_st][64 + c_in*8] = pX2;
            bf16x8 hb = {(bf16)pHa.x,(bf16)pHa.y,(bf16)pHa.z,(bf16)pHa.w,
                         (bf16)pHb.x,(bf16)pHb.y,(bf16)pHb.z,(bf16)pHb.w};
            *(bf16x8*)&Alds[m_st][128 + c_in*8] = hb;
            *(float4*)&Hlds[m_st][c_in*8]     = pHa;
            *(float4*)&Hlds[m_st][c_in*8 + 4] = pHb;
        }
        __syncthreads();                                    // (A)

        // issue next tile's loads NOW — they complete under the MFMA/epilogue
        const int tbn = tb + gridDim.x*32;
        if (tbn < NN) {
            long n = (long)tbn + m_st;
            pX1 = *(const bf16x8*)&X1[n*HH + c_in*8];
            pX2 = *(const bf16x8*)&X2[n*HH + c_in*8];
            const float4* rh = (const float4*)&H[n*HH];
            pHa = rh[c_in*2]; pHb = rh[c_in*2+1];
        }

        f32x4 accg[2][3];
        f32x4 acch[2][3];
        #pragma unroll
        for (int mt=0; mt<2; ++mt)
            #pragma unroll
            for (int jt=0; jt<3; ++jt) {
                accg[mt][jt] = (f32x4){0.f,0.f,0.f,0.f};
                acch[mt][jt] = (f32x4){0.f,0.f,0.f,0.f};
            }

        #pragma unroll
        for (int ks=0; ks<4; ++ks) {
            #pragma unroll
            for (int mt=0; mt<2; ++mt) {
                bf16x8 a = *(const bf16x8*)&Alds[mt*16 + col][ks*32 + quad*8];
                #pragma unroll
                for (int jt=0; jt<3; ++jt)
                    accg[mt][jt] = __builtin_amdgcn_mfma_f32_16x16x32_bf16(
                        a, Bg[jt][ks], accg[mt][jt], 0, 0, 0);
            }
        }
        #pragma unroll
        for (int ks=0; ks<2; ++ks) {
            #pragma unroll
            for (int mt=0; mt<2; ++mt) {
                bf16x8 a = *(const bf16x8*)&Alds[mt*16 + col][128 + ks*32 + quad*8];
                #pragma unroll
                for (int jt=0; jt<3; ++jt)
                    acch[mt][jt] = __builtin_amdgcn_mfma_f32_16x16x32_bf16(
                        a, Bh[jt][ks], acch[mt][jt], 0, 0, 0);
            }
        }

        // GRU epilogue -> Glds (bf16 tile, rows = tile rows, cols = 64 feats)
        const int c = 16*w + col;
        #pragma unroll
        for (int mt=0; mt<2; ++mt) {
            #pragma unroll
            for (int r=0; r<4; ++r) {
                float gr = accg[mt][0][r] + bgv[0];
                float gz = accg[mt][1][r] + bgv[1];
                float gn = accg[mt][2][r] + bgv[2];
                float hr = acch[mt][0][r] + bhv[0];
                float hz = acch[mt][1][r] + bhv[1];
                float hn = acch[mt][2][r] + bhv[2];
                float rr = fsig(gr + hr);
                float zz = fsig(gz + hz);
                float nv = ftanh(gn + rr*hn);
                float hv = Hlds[mt*16 + quad*4 + r][c];
                Glds[mt*16 + quad*4 + r][c] = (bf16)((1.0f - zz)*nv + zz*hv);
            }
        }
        __syncthreads();                                    // (B)

        // ---- stage 2
        if constexpr (MODE == 0) {
            f32x4 acc2[2] = {{0.f,0.f,0.f,0.f},{0.f,0.f,0.f,0.f}};
            #pragma unroll
            for (int ks=0; ks<2; ++ks)
                #pragma unroll
                for (int mt=0; mt<2; ++mt) {
                    bf16x8 a = *(const bf16x8*)&Glds[mt*16+col][ks*32+quad*8];
                    acc2[mt] = __builtin_amdgcn_mfma_f32_16x16x32_bf16(a, B2[ks], acc2[mt], 0,0,0);
                }
            #pragma unroll
            for (int mt=0; mt<2; ++mt)
                #pragma unroll
                for (int r=0; r<4; ++r)
                    Obf[(long)(tb+mt*16+quad*4+r)*HH + 16*w+col] = (bf16)(acc2[mt][r] + b2s);
        } else {
            if (w < 2) {   // 32 rows = 2 waves x 16-row M tiles; C = 16 cols
                f32x4 acc2 = {0.f,0.f,0.f,0.f};
                #pragma unroll
                for (int ks=0; ks<2; ++ks) {
                    bf16x8 a = *(const bf16x8*)&Glds[w*16+col][ks*32+quad*8];
                    acc2 = __builtin_amdgcn_mfma_f32_16x16x32_bf16(a, B2[ks], acc2, 0,0,0);
                }
                #pragma unroll
                for (int r=0; r<4; ++r) {
                    long n = tb + w*16 + quad*4 + r;
                    float val = acc2[r] + b2s;
                    float m = val;
                    #pragma unroll
                    for (int off=8; off>0; off>>=1) m = fmaxf(m, __shfl_xor(m, off, 16));
                    float ex = __expf(val - m);
                    float ssum = ex;
                    #pragma unroll
                    for (int off=8; off>0; off>>=1) ssum += __shfl_xor(ssum, off, 16);
                    Of[n*CC + col] = val - m - __logf(ssum);
                }
            }
        }
    }
}

extern "C" void kernel_launch(void* const* d_in, const int* in_sizes, int n_in,
                              void* d_out, int out_size, void* d_ws, size_t ws_size,
                              hipStream_t stream)
{
    const float* x       = (const float*)d_in[0];
    const int*   ei      = (const int*)  d_in[1];
    const float* ew      = (const float*)d_in[2];
    const int*   ei_re   = (const int*)  d_in[3];
    const float* ew_re   = (const float*)d_in[4];
    const float* W_first = (const float*)d_in[5];
    const float* b_first = (const float*)d_in[6];
    const float* W_con1  = (const float*)d_in[7];
    const float* b_con1  = (const float*)d_in[8];
    const float* W_con2  = (const float*)d_in[9];
    const float* b_con2  = (const float*)d_in[10];
    const float* W_lin1  = (const float*)d_in[11];
    const float* b_lin1  = (const float*)d_in[12];
    const float* W_out   = (const float*)d_in[13];
    const float* b_out   = (const float*)d_in[14];
    const float* W_ih    = (const float*)d_in[15];
    const float* W_hh    = (const float*)d_in[16];
    const float* b_ih    = (const float*)d_in[17];
    const float* b_hh    = (const float*)d_in[18];
    float* out = (float*)d_out;

    // ---- workspace layout (edata BEFORE rp so csr_prop's <=60B edata
    //      overread lands in the live rp array, not past ws)
    float* h    = (float*)d_ws;                // [N*64] fp32 GRU state
    bf16*  x1b  = (bf16*)(h + (long)NN*HH);    // [N*64]
    bf16*  x2b  = x1b + (long)NN*HH;           // [N*64]
    bf16*  hbf  = x2b + (long)NN*HH;           // [N*64]
    bf16*  hAbf = hbf + (long)NN*HH;           // [N*64]
    float* b1 = (float*)(hAbf + (long)NN*HH);  // [192]
    float* b2 = b1 + 192;                      // [192]
    bf16*  W1bf = (bf16*)(b2 + 192);           // [192*128]
    bf16*  W2bf = W1bf + 192*128;
    bf16*  Whbf = W2bf + 192*128;
    bf16*  Wfbf = Whbf + 192*64;
    bf16*  Wlbf = Wfbf + 64*128;
    bf16*  Wobf = Wlbf + 64*64;
    unsigned* edata = (unsigned*)(Wobf + 16*64); // [2E] packed (src,w), dst-sorted
    int*   rp     = (int*)(edata + 2*EE);      // [NSEG+1]  (doubles as edata overread pad)
    int*   bkcnt  = rp + NSEG + 1;             // [NBUK]
    int*   bkcur  = bkcnt + NBUK;              // [NBUK] (adjacent: one memset covers both)
    int*      tmp_d = (int*)x1b;               // [2E] 8 MB (aliases, dead until fillB done)
    unsigned* tmp_p = (unsigned*)x2b;          // [2E] 8 MB

    // 1) bucket-count + weight precomp (merged, independent block ranges)
    hipMemsetAsync(bkcnt, 0, (size_t)(2*NBUK)*sizeof(int), stream);
    count_precomp_kernel<<<P1BLK + PRE_BLK, 256, 0, stream>>>(
        ei, ei_re, bkcnt,
        W_ih, b_ih, W_con1, b_con1, W_con2, b_con2, W_hh, W_first, W_lin1, W_out,
        W1bf, b1, W2bf, b2, Whbf, Wfbf, Wlbf, Wobf);

    // 2) fillA (2-phase sort, phase 1; in-block global-prefix scan)
    fillA_kernel<<<P1BLK, 256, 0, stream>>>(ei, ew, ei_re, ew_re, bkcnt, bkcur, tmp_d, tmp_p);

    // 3) fillB + lin_first (merged: sort phase 2 overlaps the W_first MFMA GEMM)
    fillB_lin_kernel<<<NBUK + LINB, 1024, 0, stream>>>(
        bkcnt, tmp_d, tmp_p, edata, rp, x, Wfbf, b_first, h, hbf);

    // 4) layer-1 propagation (persistent grid, proven inner loop)
    csr_prop_kernel<<<CSRB, 256, 0, stream>>>(hbf, rp, edata, x1b, x2b);

    // 5) fused con1 + GRU + lin1 -> hAbf   (MFMA, register-prefetched staging)
    layer_fused_kernel<0><<<1024, 256, 0, stream>>>(x1b, x2b, h, W1bf, b1, Whbf, b_hh,
                                                    Wlbf, b_lin1, hAbf, nullptr);

    // 6) layer-2 propagation
    csr_prop_kernel<<<CSRB, 256, 0, stream>>>(hAbf, rp, edata, x1b, x2b);

    // 7) fused con2 + GRU + W_out + log_softmax -> out   (MFMA)
    layer_fused_kernel<1><<<1024, 256, 0, stream>>>(x1b, x2b, h, W2bf, b2, Whbf, b_hh,
                                                    Wobf, b_out, nullptr, out);
}

// Round 9
// 369.079 us; speedup vs baseline: 1.1202x; 1.0002x over previous
//
#include <hip/hip_runtime.h>

#define NN 100000
#define FF 128
#define HH 64
#define CC 16
#define EE 1000000
#define NSEG (2*NN)                 // segments: [0,NN) = fwd, [NN,2NN) = rev
#define BSH 11                      // bucket = d >> 11 (2048 dsts/bucket)
#define BKD  (1 << BSH)
#define NBUK ((NSEG + BKD - 1) / BKD)   // 98
#define EPB 4096                    // edges per fillA/bucket_count block
#define P1BLK ((2*EE + EPB - 1) / EPB)  // 489
#define PRE_TOT (192*128 + 192 + 192*64 + 64*128 + 64*64 + 16*64)  // 50368
#define PRE_BLK ((PRE_TOT + 255)/256)   // 197
#define LIN_TILES ((NN + 31)/32)        // 3125
#define LINB ((LIN_TILES + 3)/4)        // 782
#define CSRB 2048                       // persistent csr_prop grid
#define LAYB 2048                       // layer_fused grid (2/1-iter balance)

typedef __bf16 bf16;
typedef __attribute__((ext_vector_type(8))) __bf16 bf16x8;
typedef __attribute__((ext_vector_type(4))) __bf16 bf16x4;
typedef __attribute__((ext_vector_type(4))) float f32x4;
typedef __attribute__((ext_vector_type(2))) float f32x2;

__device__ __forceinline__ float fsig(float t)  { return 1.0f/(1.0f+__expf(-t)); }
__device__ __forceinline__ float ftanh(float t) { return 1.0f - 2.0f/(__expf(2.0f*t)+1.0f); }

// pack (src, w>=0) into 4 B: src(17 bits) << 15 | bf16(w) sans sign (15 bits)
__device__ __forceinline__ unsigned pack_sw(int s, float w) {
    unsigned short u = __builtin_bit_cast(unsigned short, (bf16)w);
    return ((unsigned)s << 15) | (u & 0x7FFFu);
}

// ---- precomp body (combined weights in bf16 etc.), called per flat idx
__device__ __forceinline__ void precomp_body(int idx,
                               const float* __restrict__ W_ih, const float* __restrict__ b_ih,
                               const float* __restrict__ Wc1,  const float* __restrict__ bc1,
                               const float* __restrict__ Wc2,  const float* __restrict__ bc2,
                               const float* __restrict__ W_hh, const float* __restrict__ W_first,
                               const float* __restrict__ W_lin1, const float* __restrict__ W_out,
                               bf16* __restrict__ W1bf, float* __restrict__ b1,
                               bf16* __restrict__ W2bf, float* __restrict__ b2,
                               bf16* __restrict__ Whbf, bf16* __restrict__ Wfbf,
                               bf16* __restrict__ Wlbf, bf16* __restrict__ Wobf)
{
    const int t0 = 192*128;          // W1/W2
    const int t1 = t0 + 192;         // b1/b2
    const int t2 = t1 + 192*64;      // Whbf
    const int t3 = t2 + 64*128;      // Wfbf
    const int t4 = t3 + 64*64;       // Wlbf
    const int t5 = t4 + 16*64;       // Wobf
    if (idx < t0) {
        int j = idx >> 7, k = idx & 127;
        float s1 = 0.f, s2 = 0.f;
        for (int m=0; m<64; ++m) {
            float wih = W_ih[j*64+m];
            s1 += wih * Wc1[m*128+k];
            s2 += wih * Wc2[m*128+k];
        }
        W1bf[idx] = (bf16)s1; W2bf[idx] = (bf16)s2;
    } else if (idx < t1) {
        int j = idx - t0;
        float s1 = b_ih[j], s2 = b_ih[j];
        for (int m=0; m<64; ++m) {
            float wih = W_ih[j*64+m];
            s1 += wih * bc1[m];
            s2 += wih * bc2[m];
        }
        b1[j] = s1; b2[j] = s2;
    } else if (idx < t2) {
        int i = idx - t1;  Whbf[i] = (bf16)W_hh[i];
    } else if (idx < t3) {
        int i = idx - t2;  Wfbf[i] = (bf16)W_first[i];
    } else if (idx < t4) {
        int i = idx - t3;  Wlbf[i] = (bf16)W_lin1[i];
    } else if (idx < t5) {
        int i = idx - t4;  Wobf[i] = (bf16)W_out[i];
    }
}

// ===== merged: bucket_count (blocks 0..P1BLK) + precomp (rest) =====
__global__ __launch_bounds__(256) void count_precomp_kernel(
    const int* __restrict__ ei, const int* __restrict__ ei_re, int* __restrict__ bkcnt,
    const float* __restrict__ W_ih, const float* __restrict__ b_ih,
    const float* __restrict__ Wc1,  const float* __restrict__ bc1,
    const float* __restrict__ Wc2,  const float* __restrict__ bc2,
    const float* __restrict__ W_hh, const float* __restrict__ W_first,
    const float* __restrict__ W_lin1, const float* __restrict__ W_out,
    bf16* __restrict__ W1bf, float* __restrict__ b1,
    bf16* __restrict__ W2bf, float* __restrict__ b2,
    bf16* __restrict__ Whbf, bf16* __restrict__ Wfbf,
    bf16* __restrict__ Wlbf, bf16* __restrict__ Wobf)
{
    __shared__ int hist[NBUK];
    const int t = threadIdx.x;
    if (blockIdx.x < P1BLK) {
        for (int i=t; i<NBUK; i+=256) hist[i] = 0;
        __syncthreads();
        const long e0 = (long)blockIdx.x * EPB;
        #pragma unroll
        for (int it=0; it<16; ++it) {
            long e = e0 + it*256 + t;
            int d = -1;
            if (e < EE)        d = ei[EE + e];
            else if (e < 2*EE) d = NN + ei_re[EE + (e - EE)];
            if (d >= 0) atomicAdd(&hist[d >> BSH], 1);
        }
        __syncthreads();
        for (int i=t; i<NBUK; i+=256) if (hist[i]) atomicAdd(&bkcnt[i], hist[i]);
    } else {
        int idx = (blockIdx.x - P1BLK)*256 + t;
        precomp_body(idx, W_ih, b_ih, Wc1, bc1, Wc2, bc2, W_hh, W_first, W_lin1, W_out,
                     W1bf, b1, W2bf, b2, Whbf, Wfbf, Wlbf, Wobf);
    }
}

// fillA: per-block histogram + in-block 128-thread scan of global bucket
// counts. R9: pr packs (rank<<18)|dst so pass 3 doesn't re-read the 8 MB
// dst array (d < 2^18, rank < EPB = 2^12).
__global__ __launch_bounds__(256) void fillA_kernel(const int* __restrict__ ei,
                                                    const float* __restrict__ ew,
                                                    const int* __restrict__ ei_re,
                                                    const float* __restrict__ ew_re,
                                                    const int* __restrict__ bkcnt,
                                                    int* __restrict__ bkcur,
                                                    int* __restrict__ tmp_d,
                                                    unsigned* __restrict__ tmp_p)
{
    __shared__ int hist[NBUK];
    __shared__ int base[NBUK];
    __shared__ int sc[128];
    const int t = threadIdx.x;
    for (int i=t; i<NBUK; i+=256) hist[i] = 0;
    int v = 0;
    if (t < 128) { v = (t < NBUK) ? bkcnt[t] : 0; sc[t] = v; }
    __syncthreads();
    const long e0 = (long)blockIdx.x * EPB;
    int pr[16];
    #pragma unroll
    for (int it=0; it<16; ++it) {
        long e = e0 + it*256 + t;
        int d = -1;
        if (e < EE)        d = ei[EE + e];
        else if (e < 2*EE) d = NN + ei_re[EE + (e - EE)];
        if (d >= 0) {
            int r = atomicAdd(&hist[d >> BSH], 1);
            pr[it] = (r << 18) | d;
        } else pr[it] = -1;
    }
    __syncthreads();
    #pragma unroll
    for (int off=1; off<128; off<<=1) {
        int x = 0;
        if (t >= off && t < 128) x = sc[t-off];
        __syncthreads();
        if (t < 128) sc[t] += x;
        __syncthreads();
    }
    if (t < 128 && t < NBUK) base[t] = sc[t] - v;   // exclusive global prefix
    __syncthreads();
    for (int i=t; i<NBUK; i+=256) base[i] += atomicAdd(&bkcur[i], hist[i]);
    __syncthreads();
    #pragma unroll
    for (int it=0; it<16; ++it) {
        if (pr[it] < 0) continue;
        long e = e0 + it*256 + t;
        int d = pr[it] & 0x3FFFF;
        int s; float w;
        if (e < EE) { s = ei[e]; w = ew[e]; }
        else { long j = e - EE; s = ei_re[j]; w = ew_re[j]; }
        int pos = base[d >> BSH] + (pr[it] >> 18);
        tmp_d[pos] = d;
        tmp_p[pos] = pack_sw(s, w);
    }
}

// ===== merged: fillB (blocks 0..NBUK) + lin_first (blocks NBUK..NBUK+LINB) =====
// fillB reads tmp_d/tmp_p (aliased to x1b/x2b); lin writes h/hbf — disjoint.
__global__ __launch_bounds__(1024) void fillB_lin_kernel(
    const int* __restrict__ bkcnt,
    const int* __restrict__ tmp_d, const unsigned* __restrict__ tmp_p,
    unsigned* __restrict__ edata, int* __restrict__ rp,
    const float* __restrict__ X, const bf16* __restrict__ Wf,
    const float* __restrict__ bfirst, float* __restrict__ Y, bf16* __restrict__ Ybf)
{
    __shared__ __align__(16) char smem[4*32*136*2];   // 34816 B (lin) >= 12800 B (fillB)
    const int t = threadIdx.x;
    if (blockIdx.x < NBUK) {
        int* cntL  = (int*)smem;                       // [BKD]
        int* scanL = (int*)(smem + BKD*4);             // [1024]
        int* sc98  = (int*)(smem + BKD*4 + 4096);      // [128]
        const int b  = blockIdx.x;
        const int d0 = b << BSH;
        const int dn = min(BKD, NSEG - d0);
        if (b == 0 && t == 0) rp[NSEG] = 2*EE;
        if (t < 128) sc98[t] = (t < NBUK) ? bkcnt[t] : 0;
        for (int i=t; i<BKD; i+=1024) cntL[i] = 0;
        __syncthreads();
        #pragma unroll
        for (int off=1; off<128; off<<=1) {
            int x = 0;
            if (t >= off && t < 128) x = sc98[t-off];
            __syncthreads();
            if (t < 128) sc98[t] += x;
            __syncthreads();
        }
        const int p0 = (b == 0) ? 0 : sc98[b-1];
        const int p1 = sc98[b];
        for (int pos = p0 + t; pos < p1; pos += 1024)
            atomicAdd(&cntL[tmp_d[pos] - d0], 1);
        __syncthreads();
        int a0 = cntL[2*t], a1 = cntL[2*t+1];
        int ps = a0 + a1;
        scanL[t] = ps;
        __syncthreads();
        #pragma unroll
        for (int off=1; off<1024; off<<=1) {
            int x = (t>=off) ? scanL[t-off] : 0;
            __syncthreads();
            scanL[t] += x;
            __syncthreads();
        }
        int g0 = p0 + scanL[t] - ps;
        int g1 = g0 + a0;
        if (2*t   < dn) rp[d0 + 2*t]   = g0;
        if (2*t+1 < dn) rp[d0 + 2*t+1] = g1;
        cntL[2*t]   = g0;
        cntL[2*t+1] = g1;
        __syncthreads();
        for (int pos = p0 + t; pos < p1; pos += 1024) {
            int d = tmp_d[pos];
            int p = atomicAdd(&cntL[d - d0], 1);
            edata[p] = tmp_p[pos];
        }
    } else {
        // 4 independent 256-thread lin_first tile-groups per block
        const int lb   = blockIdx.x - NBUK;
        const int sub  = t >> 8;            // 0..3
        const int tt   = t & 255;
        const int tile = lb*4 + sub;
        const bool valid = tile < LIN_TILES;
        const int tb = tile * 32;
        const int w = tt >> 6, lane = tt & 63, col = lane & 15, quad = lane >> 4;
        bf16* Alds = (bf16*)smem + sub*(32*136);    // [32][136]
        bf16x8 B[4];
        #pragma unroll
        for (int ks=0; ks<4; ++ks)
            B[ks] = *(const bf16x8*)&Wf[(16*w+col)*128 + ks*32 + quad*8];
        const float bv = bfirst[16*w + col];
        const int m_st = tt >> 3, c_in = tt & 7;
        if (valid) {
            const float4* rx = (const float4*)&X[(long)(tb+m_st)*FF];
            #pragma unroll
            for (int it=0; it<4; ++it) {
                int cc = c_in + it*8;
                float4 v = rx[cc];
                bf16x4 bvv = {(bf16)v.x,(bf16)v.y,(bf16)v.z,(bf16)v.w};
                *(bf16x4*)&Alds[m_st*136 + cc*4] = bvv;
            }
        }
        __syncthreads();
        f32x4 acc[2] = {{0.f,0.f,0.f,0.f},{0.f,0.f,0.f,0.f}};
        #pragma unroll
        for (int ks=0; ks<4; ++ks)
            #pragma unroll
            for (int mt=0; mt<2; ++mt) {
                bf16x8 a = *(const bf16x8*)&Alds[(mt*16+col)*136 + ks*32+quad*8];
                acc[mt] = __builtin_amdgcn_mfma_f32_16x16x32_bf16(a, B[ks], acc[mt], 0,0,0);
            }
        if (valid) {
            #pragma unroll
            for (int mt=0; mt<2; ++mt)
                #pragma unroll
                for (int r=0; r<4; ++r) {
                    long n = tb + mt*16 + quad*4 + r;
                    float val = acc[mt][r] + bv;
                    Y  [n*HH + 16*w+col] = val;
                    Ybf[n*HH + 16*w+col] = (bf16)val;
                }
        }
    }
}

// Quarter-wave gather segment-sum (R10/R4 proven inner loop), persistent
// grid. R9: voff UNMASKED — overread packs are either later edata entries
// (valid rows) or rp/bkcnt ints (<= 2^21 -> (p>>8)&~0x7F <= 8K, inside X);
// w is still masked to 0 so junk rows contribute nothing.
__global__ __launch_bounds__(256) void csr_prop_kernel(const bf16* __restrict__ X,
    const int* __restrict__ rp, const unsigned* __restrict__ edata,
    bf16* __restrict__ x1, bf16* __restrict__ x2)
{
    const int lane = threadIdx.x & 63;
    const int q  = lane >> 4;      // edge slot 0..3
    const int fl = lane & 15;      // feature group: 4fl .. 4fl+3
    const unsigned foff = 8u*(unsigned)fl;
    const char* Xb = (const char*)X;
    const char* Eb = (const char*)edata;

    for (int s = blockIdx.x*4 + (threadIdx.x>>6); s < NSEG; s += gridDim.x*4) {
        const int e0 = rp[s], e1 = rp[s+1];
        f32x2 acc01 = {0.f, 0.f}, acc23 = {0.f, 0.f};
        int eq = e0 + q;
        unsigned eqb = 4u*(unsigned)eq;
        for (int base = e0; base < e1; base += 16, eq += 16, eqb += 64u) {
            const int rem = e1 - eq;
            #pragma unroll
            for (int j=0; j<4; ++j) {
                unsigned p = *(const unsigned*)(Eb + (eqb + 16u*(unsigned)j));
                float w = (4*j < rem) ? __uint_as_float((p & 0x7FFFu) << 16) : 0.f;
                unsigned voff = ((p >> 8) & 0xFFFFFF80u) | foff;
                uint2 d = *(const uint2*)(Xb + voff);
                f32x2 lo = { __uint_as_float(d.x << 16), __uint_as_float(d.x & 0xFFFF0000u) };
                f32x2 hi = { __uint_as_float(d.y << 16), __uint_as_float(d.y & 0xFFFF0000u) };
                f32x2 w2 = { w, w };
                acc01 += w2 * lo;
                acc23 += w2 * hi;
            }
        }
        float a0 = acc01.x, a1 = acc01.y, a2 = acc23.x, a3 = acc23.y;
        // reduce across the 4 quarters (lanes with equal fl)
        a0 += __shfl_xor(a0, 32); a0 += __shfl_xor(a0, 16);
        a1 += __shfl_xor(a1, 32); a1 += __shfl_xor(a1, 16);
        a2 += __shfl_xor(a2, 32); a2 += __shfl_xor(a2, 16);
        a3 += __shfl_xor(a3, 32); a3 += __shfl_xor(a3, 16);
        if (q == 0) {
            bf16* o = (s < NN) ? &x1[(long)s*HH] : &x2[(long)(s-NN)*HH];
            bf16x4 ov = {(bf16)a0, (bf16)a1, (bf16)a2, (bf16)a3};
            *(bf16x4*)&o[4*fl] = ov;
        }
    }
}

// Fused con+GRU layer, second MFMA stage through Glds; fp32 hA eliminated.
//   MODE 0: stage2 = W_lin1 (64x64) -> bf16 Obf
//   MODE 1: stage2 = W_out  (16x64) + log_softmax -> f32 Of
template<int MODE>
__global__ __launch_bounds__(256, 2) void layer_fused_kernel(
    const bf16* __restrict__ X1, const bf16* __restrict__ X2,
    const float* __restrict__ H,
    const bf16* __restrict__ Wg, const float* __restrict__ bg,
    const bf16* __restrict__ Wh, const float* __restrict__ bh,
    const bf16* __restrict__ Ws, const float* __restrict__ bs,
    bf16* __restrict__ Obf, float* __restrict__ Of)
{
    const int t    = threadIdx.x;
    const int w    = t >> 6;
    const int lane = t & 63;
    const int col  = lane & 15;
    const int quad = lane >> 4;

    bf16x8 Bg[3][4];
    bf16x8 Bh[3][2];
    float bgv[3], bhv[3];
    #pragma unroll
    for (int jt=0; jt<3; ++jt) {
        int J = jt*64 + 16*w + col;
        #pragma unroll
        for (int ks=0; ks<4; ++ks)
            Bg[jt][ks] = *(const bf16x8*)&Wg[J*128 + ks*32 + quad*8];
        #pragma unroll
        for (int ks=0; ks<2; ++ks)
            Bh[jt][ks] = *(const bf16x8*)&Wh[J*64 + ks*32 + quad*8];
        bgv[jt] = bg[J];
        bhv[jt] = bh[J];
    }

    bf16x8 B2[2];
    float b2s;
    if constexpr (MODE == 0) {
        #pragma unroll
        for (int ks=0; ks<2; ++ks)
            B2[ks] = *(const bf16x8*)&Ws[(16*w+col)*64 + ks*32 + quad*8];
        b2s = bs[16*w + col];
    } else {
        #pragma unroll
        for (int ks=0; ks<2; ++ks)
            B2[ks] = *(const bf16x8*)&Ws[col*64 + ks*32 + quad*8];
        b2s = bs[col];
    }

    __shared__ bf16  Alds[32][200];
    __shared__ bf16  Glds[32][72];   // GRU output tile (bf16), stage-2 A operand
    __shared__ float Hlds[32][66];   // fp32 H tile for the epilogue

    const int m_st = t >> 3;
    const int c_in = t & 7;

    // prefetch first tile into registers
    bf16x8 pX1, pX2;
    float4 pHa, pHb;
    {
        long n = (long)blockIdx.x*32 + m_st;
        pX1 = *(const bf16x8*)&X1[n*HH + c_in*8];
        pX2 = *(const bf16x8*)&X2[n*HH + c_in*8];
        const float4* rh = (const float4*)&H[n*HH];
        pHa = rh[c_in*2]; pHb = rh[c_in*2+1];
    }

    for (int tb = blockIdx.x*32; tb < NN; tb += gridDim.x*32) {
        {
            *(bf16x8*)&Alds[m_st][c_in*8]      = pX1;
            *(bf16x8*)&Alds[m_st][64 + c_in*8] = pX2;
            bf16x8 hb = {(bf16)pHa.x,(bf16)pHa.y,(bf16)pHa.z,(bf16)pHa.w,
                         (bf16)pHb.x,(bf16)pHb.y,(bf16)pHb.z,(bf16)pHb.w};
            *(bf16x8*)&Alds[m_st][128 + c_in*8] = hb;
            *(float4*)&Hlds[m_st][c_in*8]     = pHa;
            *(float4*)&Hlds[m_st][c_in*8 + 4] = pHb;
        }
        __syncthreads();                                    // (A)

        // issue next tile's loads NOW — they complete under the MFMA/epilogue
        const int tbn = tb + gridDim.x*32;
        if (tbn < NN) {
            long n = (long)tbn + m_st;
            pX1 = *(const bf16x8*)&X1[n*HH + c_in*8];
            pX2 = *(const bf16x8*)&X2[n*HH + c_in*8];
            const float4* rh = (const float4*)&H[n*HH];
            pHa = rh[c_in*2]; pHb = rh[c_in*2+1];
        }

        f32x4 accg[2][3];
        f32x4 acch[2][3];
        #pragma unroll
        for (int mt=0; mt<2; ++mt)
            #pragma unroll
            for (int jt=0; jt<3; ++jt) {
                accg[mt][jt] = (f32x4){0.f,0.f,0.f,0.f};
                acch[mt][jt] = (f32x4){0.f,0.f,0.f,0.f};
            }

        #pragma unroll
        for (int ks=0; ks<4; ++ks) {
            #pragma unroll
            for (int mt=0; mt<2; ++mt) {
                bf16x8 a = *(const bf16x8*)&Alds[mt*16 + col][ks*32 + quad*8];
                #pragma unroll
                for (int jt=0; jt<3; ++jt)
                    accg[mt][jt] = __builtin_amdgcn_mfma_f32_16x16x32_bf16(
                        a, Bg[jt][ks], accg[mt][jt], 0, 0, 0);
            }
        }
        #pragma unroll
        for (int ks=0; ks<2; ++ks) {
            #pragma unroll
            for (int mt=0; mt<2; ++mt) {
                bf16x8 a = *(const bf16x8*)&Alds[mt*16 + col][128 + ks*32 + quad*8];
                #pragma unroll
                for (int jt=0; jt<3; ++jt)
                    acch[mt][jt] = __builtin_amdgcn_mfma_f32_16x16x32_bf16(
                        a, Bh[jt][ks], acch[mt][jt], 0, 0, 0);
            }
        }

        // GRU epilogue -> Glds (bf16 tile, rows = tile rows, cols = 64 feats)
        const int c = 16*w + col;
        #pragma unroll
        for (int mt=0; mt<2; ++mt) {
            #pragma unroll
            for (int r=0; r<4; ++r) {
                float gr = accg[mt][0][r] + bgv[0];
                float gz = accg[mt][1][r] + bgv[1];
                float gn = accg[mt][2][r] + bgv[2];
                float hr = acch[mt][0][r] + bhv[0];
                float hz = acch[mt][1][r] + bhv[1];
                float hn = acch[mt][2][r] + bhv[2];
                float rr = fsig(gr + hr);
                float zz = fsig(gz + hz);
                float nv = ftanh(gn + rr*hn);
                float hv = Hlds[mt*16 + quad*4 + r][c];
                Glds[mt*16 + quad*4 + r][c] = (bf16)((1.0f - zz)*nv + zz*hv);
            }
        }
        __syncthreads();                                    // (B)

        // ---- stage 2
        if constexpr (MODE == 0) {
            f32x4 acc2[2] = {{0.f,0.f,0.f,0.f},{0.f,0.f,0.f,0.f}};
            #pragma unroll
            for (int ks=0; ks<2; ++ks)
                #pragma unroll
                for (int mt=0; mt<2; ++mt) {
                    bf16x8 a = *(const bf16x8*)&Glds[mt*16+col][ks*32+quad*8];
                    acc2[mt] = __builtin_amdgcn_mfma_f32_16x16x32_bf16(a, B2[ks], acc2[mt], 0,0,0);
                }
            #pragma unroll
            for (int mt=0; mt<2; ++mt)
                #pragma unroll
                for (int r=0; r<4; ++r)
                    Obf[(long)(tb+mt*16+quad*4+r)*HH + 16*w+col] = (bf16)(acc2[mt][r] + b2s);
        } else {
            if (w < 2) {   // 32 rows = 2 waves x 16-row M tiles; C = 16 cols
                f32x4 acc2 = {0.f,0.f,0.f,0.f};
                #pragma unroll
                for (int ks=0; ks<2; ++ks) {
                    bf16x8 a = *(const bf16x8*)&Glds[w*16+col][ks*32+quad*8];
                    acc2 = __builtin_amdgcn_mfma_f32_16x16x32_bf16(a, B2[ks], acc2, 0,0,0);
                }
                #pragma unroll
                for (int r=0; r<4; ++r) {
                    long n = tb + w*16 + quad*4 + r;
                    float val = acc2[r] + b2s;
                    float m = val;
                    #pragma unroll
                    for (int off=8; off>0; off>>=1) m = fmaxf(m, __shfl_xor(m, off, 16));
                    float ex = __expf(val - m);
                    float ssum = ex;
                    #pragma unroll
                    for (int off=8; off>0; off>>=1) ssum += __shfl_xor(ssum, off, 16);
                    Of[n*CC + col] = val - m - __logf(ssum);
                }
            }
        }
    }
}

extern "C" void kernel_launch(void* const* d_in, const int* in_sizes, int n_in,
                              void* d_out, int out_size, void* d_ws, size_t ws_size,
                              hipStream_t stream)
{
    const float* x       = (const float*)d_in[0];
    const int*   ei      = (const int*)  d_in[1];
    const float* ew      = (const float*)d_in[2];
    const int*   ei_re   = (const int*)  d_in[3];
    const float* ew_re   = (const float*)d_in[4];
    const float* W_first = (const float*)d_in[5];
    const float* b_first = (const float*)d_in[6];
    const float* W_con1  = (const float*)d_in[7];
    const float* b_con1  = (const float*)d_in[8];
    const float* W_con2  = (const float*)d_in[9];
    const float* b_con2  = (const float*)d_in[10];
    const float* W_lin1  = (const float*)d_in[11];
    const float* b_lin1  = (const float*)d_in[12];
    const float* W_out   = (const float*)d_in[13];
    const float* b_out   = (const float*)d_in[14];
    const float* W_ih    = (const float*)d_in[15];
    const float* W_hh    = (const float*)d_in[16];
    const float* b_ih    = (const float*)d_in[17];
    const float* b_hh    = (const float*)d_in[18];
    float* out = (float*)d_out;

    // ---- workspace layout (edata BEFORE rp so csr_prop's <=60B edata
    //      overread lands in the live rp array, not past ws)
    float* h    = (float*)d_ws;                // [N*64] fp32 GRU state
    bf16*  x1b  = (bf16*)(h + (long)NN*HH);    // [N*64]
    bf16*  x2b  = x1b + (long)NN*HH;           // [N*64]
    bf16*  hbf  = x2b + (long)NN*HH;           // [N*64]
    bf16*  hAbf = hbf + (long)NN*HH;           // [N*64]
    float* b1 = (float*)(hAbf + (long)NN*HH);  // [192]
    float* b2 = b1 + 192;                      // [192]
    bf16*  W1bf = (bf16*)(b2 + 192);           // [192*128]
    bf16*  W2bf = W1bf + 192*128;
    bf16*  Whbf = W2bf + 192*128;
    bf16*  Wfbf = Whbf + 192*64;
    bf16*  Wlbf = Wfbf + 64*128;
    bf16*  Wobf = Wlbf + 64*64;
    unsigned* edata = (unsigned*)(Wobf + 16*64); // [2E] packed (src,w), dst-sorted
    int*   rp     = (int*)(edata + 2*EE);      // [NSEG+1]  (doubles as edata overread pad)
    int*   bkcnt  = rp + NSEG + 1;             // [NBUK]
    int*   bkcur  = bkcnt + NBUK;              // [NBUK] (adjacent: one memset covers both)
    int*      tmp_d = (int*)x1b;               // [2E] 8 MB (aliases, dead until fillB done)
    unsigned* tmp_p = (unsigned*)x2b;          // [2E] 8 MB

    // 1) bucket-count + weight precomp (merged, independent block ranges)
    hipMemsetAsync(bkcnt, 0, (size_t)(2*NBUK)*sizeof(int), stream);
    count_precomp_kernel<<<P1BLK + PRE_BLK, 256, 0, stream>>>(
        ei, ei_re, bkcnt,
        W_ih, b_ih, W_con1, b_con1, W_con2, b_con2, W_hh, W_first, W_lin1, W_out,
        W1bf, b1, W2bf, b2, Whbf, Wfbf, Wlbf, Wobf);

    // 2) fillA (2-phase sort, phase 1; in-block global-prefix scan)
    fillA_kernel<<<P1BLK, 256, 0, stream>>>(ei, ew, ei_re, ew_re, bkcnt, bkcur, tmp_d, tmp_p);

    // 3) fillB + lin_first (merged: sort phase 2 overlaps the W_first MFMA GEMM)
    fillB_lin_kernel<<<NBUK + LINB, 1024, 0, stream>>>(
        bkcnt, tmp_d, tmp_p, edata, rp, x, Wfbf, b_first, h, hbf);

    // 4) layer-1 propagation (persistent grid, proven inner loop)
    csr_prop_kernel<<<CSRB, 256, 0, stream>>>(hbf, rp, edata, x1b, x2b);

    // 5) fused con1 + GRU + lin1 -> hAbf   (MFMA)
    layer_fused_kernel<0><<<LAYB, 256, 0, stream>>>(x1b, x2b, h, W1bf, b1, Whbf, b_hh,
                                                    Wlbf, b_lin1, hAbf, nullptr);

    // 6) layer-2 propagation
    csr_prop_kernel<<<CSRB, 256, 0, stream>>>(hAbf, rp, edata, x1b, x2b);

    // 7) fused con2 + GRU + W_out + log_softmax -> out   (MFMA)
    layer_fused_kernel<1><<<LAYB, 256, 0, stream>>>(x1b, x2b, h, W2bf, b2, Whbf, b_hh,
                                                    Wobf, b_out, nullptr, out);
}

// Round 10
// 367.001 us; speedup vs baseline: 1.1265x; 1.0057x over previous
//
#include <hip/hip_runtime.h>

#define NN 100000
#define FF 128
#define HH 64
#define CC 16
#define EE 1000000
#define NSEG (2*NN)                 // segments: [0,NN) = fwd, [NN,2NN) = rev
#define BSH 11                      // bucket = d >> 11 (2048 dsts/bucket)
#define BKD  (1 << BSH)
#define NBUK ((NSEG + BKD - 1) / BKD)   // 98
#define EPB 4096                    // edges per fillA/bucket_count block
#define P1BLK ((2*EE + EPB - 1) / EPB)  // 489
#define PRE_TOT (192*128 + 192 + 192*64 + 64*128 + 64*64 + 16*64)  // 50368
#define PRE_BLK ((PRE_TOT + 255)/256)   // 197
#define LIN_TILES ((NN + 31)/32)        // 3125
#define LINB ((LIN_TILES + 3)/4)        // 782
#define CSRB 2048                       // persistent csr_prop grid
#define LAYB 2048                       // layer_fused grid (2/1-iter balance)

typedef __bf16 bf16;
typedef __attribute__((ext_vector_type(8))) __bf16 bf16x8;
typedef __attribute__((ext_vector_type(4))) __bf16 bf16x4;
typedef __attribute__((ext_vector_type(4))) float f32x4;
typedef __attribute__((ext_vector_type(2))) float f32x2;

// R10: single-instruction v_rcp_f32 instead of the precise-division
// sequence (v_div_scale+rcp+fmas+fixup, ~10 instr) — ~1 ULP, invisible
// under the bf16 quantum that dominates absmax.
__device__ __forceinline__ float frcp(float t)  { return __builtin_amdgcn_rcpf(t); }
__device__ __forceinline__ float fsig(float t)  { return frcp(1.0f+__expf(-t)); }
__device__ __forceinline__ float ftanh(float t) { return 1.0f - 2.0f*frcp(__expf(2.0f*t)+1.0f); }

// pack (src, w>=0) into 4 B: src(17 bits) << 15 | bf16(w) sans sign (15 bits)
__device__ __forceinline__ unsigned pack_sw(int s, float w) {
    unsigned short u = __builtin_bit_cast(unsigned short, (bf16)w);
    return ((unsigned)s << 15) | (u & 0x7FFFu);
}

// ---- precomp body (combined weights in bf16 etc.), called per flat idx
__device__ __forceinline__ void precomp_body(int idx,
                               const float* __restrict__ W_ih, const float* __restrict__ b_ih,
                               const float* __restrict__ Wc1,  const float* __restrict__ bc1,
                               const float* __restrict__ Wc2,  const float* __restrict__ bc2,
                               const float* __restrict__ W_hh, const float* __restrict__ W_first,
                               const float* __restrict__ W_lin1, const float* __restrict__ W_out,
                               bf16* __restrict__ W1bf, float* __restrict__ b1,
                               bf16* __restrict__ W2bf, float* __restrict__ b2,
                               bf16* __restrict__ Whbf, bf16* __restrict__ Wfbf,
                               bf16* __restrict__ Wlbf, bf16* __restrict__ Wobf)
{
    const int t0 = 192*128;          // W1/W2
    const int t1 = t0 + 192;         // b1/b2
    const int t2 = t1 + 192*64;      // Whbf
    const int t3 = t2 + 64*128;      // Wfbf
    const int t4 = t3 + 64*64;       // Wlbf
    const int t5 = t4 + 16*64;       // Wobf
    if (idx < t0) {
        int j = idx >> 7, k = idx & 127;
        float s1 = 0.f, s2 = 0.f;
        for (int m=0; m<64; ++m) {
            float wih = W_ih[j*64+m];
            s1 += wih * Wc1[m*128+k];
            s2 += wih * Wc2[m*128+k];
        }
        W1bf[idx] = (bf16)s1; W2bf[idx] = (bf16)s2;
    } else if (idx < t1) {
        int j = idx - t0;
        float s1 = b_ih[j], s2 = b_ih[j];
        for (int m=0; m<64; ++m) {
            float wih = W_ih[j*64+m];
            s1 += wih * bc1[m];
            s2 += wih * bc2[m];
        }
        b1[j] = s1; b2[j] = s2;
    } else if (idx < t2) {
        int i = idx - t1;  Whbf[i] = (bf16)W_hh[i];
    } else if (idx < t3) {
        int i = idx - t2;  Wfbf[i] = (bf16)W_first[i];
    } else if (idx < t4) {
        int i = idx - t3;  Wlbf[i] = (bf16)W_lin1[i];
    } else if (idx < t5) {
        int i = idx - t4;  Wobf[i] = (bf16)W_out[i];
    }
}

// ===== merged: bucket_count (blocks 0..P1BLK) + precomp (rest) =====
__global__ __launch_bounds__(256) void count_precomp_kernel(
    const int* __restrict__ ei, const int* __restrict__ ei_re, int* __restrict__ bkcnt,
    const float* __restrict__ W_ih, const float* __restrict__ b_ih,
    const float* __restrict__ Wc1,  const float* __restrict__ bc1,
    const float* __restrict__ Wc2,  const float* __restrict__ bc2,
    const float* __restrict__ W_hh, const float* __restrict__ W_first,
    const float* __restrict__ W_lin1, const float* __restrict__ W_out,
    bf16* __restrict__ W1bf, float* __restrict__ b1,
    bf16* __restrict__ W2bf, float* __restrict__ b2,
    bf16* __restrict__ Whbf, bf16* __restrict__ Wfbf,
    bf16* __restrict__ Wlbf, bf16* __restrict__ Wobf)
{
    __shared__ int hist[NBUK];
    const int t = threadIdx.x;
    if (blockIdx.x < P1BLK) {
        for (int i=t; i<NBUK; i+=256) hist[i] = 0;
        __syncthreads();
        const long e0 = (long)blockIdx.x * EPB;
        #pragma unroll
        for (int it=0; it<16; ++it) {
            long e = e0 + it*256 + t;
            int d = -1;
            if (e < EE)        d = ei[EE + e];
            else if (e < 2*EE) d = NN + ei_re[EE + (e - EE)];
            if (d >= 0) atomicAdd(&hist[d >> BSH], 1);
        }
        __syncthreads();
        for (int i=t; i<NBUK; i+=256) if (hist[i]) atomicAdd(&bkcnt[i], hist[i]);
    } else {
        int idx = (blockIdx.x - P1BLK)*256 + t;
        precomp_body(idx, W_ih, b_ih, Wc1, bc1, Wc2, bc2, W_hh, W_first, W_lin1, W_out,
                     W1bf, b1, W2bf, b2, Whbf, Wfbf, Wlbf, Wobf);
    }
}

// fillA: per-block histogram + in-block 128-thread scan of global bucket
// counts; pr packs (rank<<18)|dst so pass 3 doesn't re-read the dst array.
__global__ __launch_bounds__(256) void fillA_kernel(const int* __restrict__ ei,
                                                    const float* __restrict__ ew,
                                                    const int* __restrict__ ei_re,
                                                    const float* __restrict__ ew_re,
                                                    const int* __restrict__ bkcnt,
                                                    int* __restrict__ bkcur,
                                                    int* __restrict__ tmp_d,
                                                    unsigned* __restrict__ tmp_p)
{
    __shared__ int hist[NBUK];
    __shared__ int base[NBUK];
    __shared__ int sc[128];
    const int t = threadIdx.x;
    for (int i=t; i<NBUK; i+=256) hist[i] = 0;
    int v = 0;
    if (t < 128) { v = (t < NBUK) ? bkcnt[t] : 0; sc[t] = v; }
    __syncthreads();
    const long e0 = (long)blockIdx.x * EPB;
    int pr[16];
    #pragma unroll
    for (int it=0; it<16; ++it) {
        long e = e0 + it*256 + t;
        int d = -1;
        if (e < EE)        d = ei[EE + e];
        else if (e < 2*EE) d = NN + ei_re[EE + (e - EE)];
        if (d >= 0) {
            int r = atomicAdd(&hist[d >> BSH], 1);
            pr[it] = (r << 18) | d;
        } else pr[it] = -1;
    }
    __syncthreads();
    #pragma unroll
    for (int off=1; off<128; off<<=1) {
        int x = 0;
        if (t >= off && t < 128) x = sc[t-off];
        __syncthreads();
        if (t < 128) sc[t] += x;
        __syncthreads();
    }
    if (t < 128 && t < NBUK) base[t] = sc[t] - v;   // exclusive global prefix
    __syncthreads();
    for (int i=t; i<NBUK; i+=256) base[i] += atomicAdd(&bkcur[i], hist[i]);
    __syncthreads();
    #pragma unroll
    for (int it=0; it<16; ++it) {
        if (pr[it] < 0) continue;
        long e = e0 + it*256 + t;
        int d = pr[it] & 0x3FFFF;
        int s; float w;
        if (e < EE) { s = ei[e]; w = ew[e]; }
        else { long j = e - EE; s = ei_re[j]; w = ew_re[j]; }
        int pos = base[d >> BSH] + (pr[it] >> 18);
        tmp_d[pos] = d;
        tmp_p[pos] = pack_sw(s, w);
    }
}

// ===== merged: fillB (blocks 0..NBUK) + lin_first (blocks NBUK..NBUK+LINB) =====
// fillB reads tmp_d/tmp_p (aliased to x1b/x2b); lin writes h/hbf — disjoint.
__global__ __launch_bounds__(1024) void fillB_lin_kernel(
    const int* __restrict__ bkcnt,
    const int* __restrict__ tmp_d, const unsigned* __restrict__ tmp_p,
    unsigned* __restrict__ edata, int* __restrict__ rp,
    const float* __restrict__ X, const bf16* __restrict__ Wf,
    const float* __restrict__ bfirst, float* __restrict__ Y, bf16* __restrict__ Ybf)
{
    __shared__ __align__(16) char smem[4*32*136*2];   // 34816 B (lin) >= 12800 B (fillB)
    const int t = threadIdx.x;
    if (blockIdx.x < NBUK) {
        int* cntL  = (int*)smem;                       // [BKD]
        int* scanL = (int*)(smem + BKD*4);             // [1024]
        int* sc98  = (int*)(smem + BKD*4 + 4096);      // [128]
        const int b  = blockIdx.x;
        const int d0 = b << BSH;
        const int dn = min(BKD, NSEG - d0);
        if (b == 0 && t == 0) rp[NSEG] = 2*EE;
        if (t < 128) sc98[t] = (t < NBUK) ? bkcnt[t] : 0;
        for (int i=t; i<BKD; i+=1024) cntL[i] = 0;
        __syncthreads();
        #pragma unroll
        for (int off=1; off<128; off<<=1) {
            int x = 0;
            if (t >= off && t < 128) x = sc98[t-off];
            __syncthreads();
            if (t < 128) sc98[t] += x;
            __syncthreads();
        }
        const int p0 = (b == 0) ? 0 : sc98[b-1];
        const int p1 = sc98[b];
        for (int pos = p0 + t; pos < p1; pos += 1024)
            atomicAdd(&cntL[tmp_d[pos] - d0], 1);
        __syncthreads();
        int a0 = cntL[2*t], a1 = cntL[2*t+1];
        int ps = a0 + a1;
        scanL[t] = ps;
        __syncthreads();
        #pragma unroll
        for (int off=1; off<1024; off<<=1) {
            int x = (t>=off) ? scanL[t-off] : 0;
            __syncthreads();
            scanL[t] += x;
            __syncthreads();
        }
        int g0 = p0 + scanL[t] - ps;
        int g1 = g0 + a0;
        if (2*t   < dn) rp[d0 + 2*t]   = g0;
        if (2*t+1 < dn) rp[d0 + 2*t+1] = g1;
        cntL[2*t]   = g0;
        cntL[2*t+1] = g1;
        __syncthreads();
        for (int pos = p0 + t; pos < p1; pos += 1024) {
            int d = tmp_d[pos];
            int p = atomicAdd(&cntL[d - d0], 1);
            edata[p] = tmp_p[pos];
        }
    } else {
        // 4 independent 256-thread lin_first tile-groups per block
        const int lb   = blockIdx.x - NBUK;
        const int sub  = t >> 8;            // 0..3
        const int tt   = t & 255;
        const int tile = lb*4 + sub;
        const bool valid = tile < LIN_TILES;
        const int tb = tile * 32;
        const int w = tt >> 6, lane = tt & 63, col = lane & 15, quad = lane >> 4;
        bf16* Alds = (bf16*)smem + sub*(32*136);    // [32][136]
        bf16x8 B[4];
        #pragma unroll
        for (int ks=0; ks<4; ++ks)
            B[ks] = *(const bf16x8*)&Wf[(16*w+col)*128 + ks*32 + quad*8];
        const float bv = bfirst[16*w + col];
        const int m_st = tt >> 3, c_in = tt & 7;
        if (valid) {
            const float4* rx = (const float4*)&X[(long)(tb+m_st)*FF];
            #pragma unroll
            for (int it=0; it<4; ++it) {
                int cc = c_in + it*8;
                float4 v = rx[cc];
                bf16x4 bvv = {(bf16)v.x,(bf16)v.y,(bf16)v.z,(bf16)v.w};
                *(bf16x4*)&Alds[m_st*136 + cc*4] = bvv;
            }
        }
        __syncthreads();
        f32x4 acc[2] = {{0.f,0.f,0.f,0.f},{0.f,0.f,0.f,0.f}};
        #pragma unroll
        for (int ks=0; ks<4; ++ks)
            #pragma unroll
            for (int mt=0; mt<2; ++mt) {
                bf16x8 a = *(const bf16x8*)&Alds[(mt*16+col)*136 + ks*32+quad*8];
                acc[mt] = __builtin_amdgcn_mfma_f32_16x16x32_bf16(a, B[ks], acc[mt], 0,0,0);
            }
        if (valid) {
            #pragma unroll
            for (int mt=0; mt<2; ++mt)
                #pragma unroll
                for (int r=0; r<4; ++r) {
                    long n = tb + mt*16 + quad*4 + r;
                    float val = acc[mt][r] + bv;
                    Y  [n*HH + 16*w+col] = val;
                    Ybf[n*HH + 16*w+col] = (bf16)val;
                }
        }
    }
}

// Quarter-wave gather segment-sum (R10/R4 proven inner loop), persistent
// grid; voff unmasked (overread rows valid or tiny offsets), w masked 0.
__global__ __launch_bounds__(256) void csr_prop_kernel(const bf16* __restrict__ X,
    const int* __restrict__ rp, const unsigned* __restrict__ edata,
    bf16* __restrict__ x1, bf16* __restrict__ x2)
{
    const int lane = threadIdx.x & 63;
    const int q  = lane >> 4;      // edge slot 0..3
    const int fl = lane & 15;      // feature group: 4fl .. 4fl+3
    const unsigned foff = 8u*(unsigned)fl;
    const char* Xb = (const char*)X;
    const char* Eb = (const char*)edata;

    for (int s = blockIdx.x*4 + (threadIdx.x>>6); s < NSEG; s += gridDim.x*4) {
        const int e0 = rp[s], e1 = rp[s+1];
        f32x2 acc01 = {0.f, 0.f}, acc23 = {0.f, 0.f};
        int eq = e0 + q;
        unsigned eqb = 4u*(unsigned)eq;
        for (int base = e0; base < e1; base += 16, eq += 16, eqb += 64u) {
            const int rem = e1 - eq;
            #pragma unroll
            for (int j=0; j<4; ++j) {
                unsigned p = *(const unsigned*)(Eb + (eqb + 16u*(unsigned)j));
                float w = (4*j < rem) ? __uint_as_float((p & 0x7FFFu) << 16) : 0.f;
                unsigned voff = ((p >> 8) & 0xFFFFFF80u) | foff;
                uint2 d = *(const uint2*)(Xb + voff);
                f32x2 lo = { __uint_as_float(d.x << 16), __uint_as_float(d.x & 0xFFFF0000u) };
                f32x2 hi = { __uint_as_float(d.y << 16), __uint_as_float(d.y & 0xFFFF0000u) };
                f32x2 w2 = { w, w };
                acc01 += w2 * lo;
                acc23 += w2 * hi;
            }
        }
        float a0 = acc01.x, a1 = acc01.y, a2 = acc23.x, a3 = acc23.y;
        // reduce across the 4 quarters (lanes with equal fl)
        a0 += __shfl_xor(a0, 32); a0 += __shfl_xor(a0, 16);
        a1 += __shfl_xor(a1, 32); a1 += __shfl_xor(a1, 16);
        a2 += __shfl_xor(a2, 32); a2 += __shfl_xor(a2, 16);
        a3 += __shfl_xor(a3, 32); a3 += __shfl_xor(a3, 16);
        if (q == 0) {
            bf16* o = (s < NN) ? &x1[(long)s*HH] : &x2[(long)(s-NN)*HH];
            bf16x4 ov = {(bf16)a0, (bf16)a1, (bf16)a2, (bf16)a3};
            *(bf16x4*)&o[4*fl] = ov;
        }
    }
}

// Fused con+GRU layer, second MFMA stage through Glds; fp32 hA eliminated.
//   MODE 0: stage2 = W_lin1 (64x64) -> bf16 Obf
//   MODE 1: stage2 = W_out  (16x64) + log_softmax -> f32 Of
template<int MODE>
__global__ __launch_bounds__(256, 2) void layer_fused_kernel(
    const bf16* __restrict__ X1, const bf16* __restrict__ X2,
    const float* __restrict__ H,
    const bf16* __restrict__ Wg, const float* __restrict__ bg,
    const bf16* __restrict__ Wh, const float* __restrict__ bh,
    const bf16* __restrict__ Ws, const float* __restrict__ bs,
    bf16* __restrict__ Obf, float* __restrict__ Of)
{
    const int t    = threadIdx.x;
    const int w    = t >> 6;
    const int lane = t & 63;
    const int col  = lane & 15;
    const int quad = lane >> 4;

    bf16x8 Bg[3][4];
    bf16x8 Bh[3][2];
    float bgv[3], bhv[3];
    #pragma unroll
    for (int jt=0; jt<3; ++jt) {
        int J = jt*64 + 16*w + col;
        #pragma unroll
        for (int ks=0; ks<4; ++ks)
            Bg[jt][ks] = *(const bf16x8*)&Wg[J*128 + ks*32 + quad*8];
        #pragma unroll
        for (int ks=0; ks<2; ++ks)
            Bh[jt][ks] = *(const bf16x8*)&Wh[J*64 + ks*32 + quad*8];
        bgv[jt] = bg[J];
        bhv[jt] = bh[J];
    }

    bf16x8 B2[2];
    float b2s;
    if constexpr (MODE == 0) {
        #pragma unroll
        for (int ks=0; ks<2; ++ks)
            B2[ks] = *(const bf16x8*)&Ws[(16*w+col)*64 + ks*32 + quad*8];
        b2s = bs[16*w + col];
    } else {
        #pragma unroll
        for (int ks=0; ks<2; ++ks)
            B2[ks] = *(const bf16x8*)&Ws[col*64 + ks*32 + quad*8];
        b2s = bs[col];
    }

    __shared__ bf16  Alds[32][200];
    __shared__ bf16  Glds[32][72];   // GRU output tile (bf16), stage-2 A operand
    __shared__ float Hlds[32][66];   // fp32 H tile for the epilogue

    const int m_st = t >> 3;
    const int c_in = t & 7;

    // prefetch first tile into registers
    bf16x8 pX1, pX2;
    float4 pHa, pHb;
    {
        long n = (long)blockIdx.x*32 + m_st;
        pX1 = *(const bf16x8*)&X1[n*HH + c_in*8];
        pX2 = *(const bf16x8*)&X2[n*HH + c_in*8];
        const float4* rh = (const float4*)&H[n*HH];
        pHa = rh[c_in*2]; pHb = rh[c_in*2+1];
    }

    for (int tb = blockIdx.x*32; tb < NN; tb += gridDim.x*32) {
        {
            *(bf16x8*)&Alds[m_st][c_in*8]      = pX1;
            *(bf16x8*)&Alds[m_st][64 + c_in*8] = pX2;
            bf16x8 hb = {(bf16)pHa.x,(bf16)pHa.y,(bf16)pHa.z,(bf16)pHa.w,
                         (bf16)pHb.x,(bf16)pHb.y,(bf16)pHb.z,(bf16)pHb.w};
            *(bf16x8*)&Alds[m_st][128 + c_in*8] = hb;
            *(float4*)&Hlds[m_st][c_in*8]     = pHa;
            *(float4*)&Hlds[m_st][c_in*8 + 4] = pHb;
        }
        __syncthreads();                                    // (A)

        // issue next tile's loads NOW — they complete under the MFMA/epilogue
        const int tbn = tb + gridDim.x*32;
        if (tbn < NN) {
            long n = (long)tbn + m_st;
            pX1 = *(const bf16x8*)&X1[n*HH + c_in*8];
            pX2 = *(const bf16x8*)&X2[n*HH + c_in*8];
            const float4* rh = (const float4*)&H[n*HH];
            pHa = rh[c_in*2]; pHb = rh[c_in*2+1];
        }

        f32x4 accg[2][3];
        f32x4 acch[2][3];
        #pragma unroll
        for (int mt=0; mt<2; ++mt)
            #pragma unroll
            for (int jt=0; jt<3; ++jt) {
                accg[mt][jt] = (f32x4){0.f,0.f,0.f,0.f};
                acch[mt][jt] = (f32x4){0.f,0.f,0.f,0.f};
            }

        #pragma unroll
        for (int ks=0; ks<4; ++ks) {
            #pragma unroll
            for (int mt=0; mt<2; ++mt) {
                bf16x8 a = *(const bf16x8*)&Alds[mt*16 + col][ks*32 + quad*8];
                #pragma unroll
                for (int jt=0; jt<3; ++jt)
                    accg[mt][jt] = __builtin_amdgcn_mfma_f32_16x16x32_bf16(
                        a, Bg[jt][ks], accg[mt][jt], 0, 0, 0);
            }
        }
        #pragma unroll
        for (int ks=0; ks<2; ++ks) {
            #pragma unroll
            for (int mt=0; mt<2; ++mt) {
                bf16x8 a = *(const bf16x8*)&Alds[mt*16 + col][128 + ks*32 + quad*8];
                #pragma unroll
                for (int jt=0; jt<3; ++jt)
                    acch[mt][jt] = __builtin_amdgcn_mfma_f32_16x16x32_bf16(
                        a, Bh[jt][ks], acch[mt][jt], 0, 0, 0);
            }
        }

        // GRU epilogue -> Glds (bf16 tile, rows = tile rows, cols = 64 feats)
        const int c = 16*w + col;
        #pragma unroll
        for (int mt=0; mt<2; ++mt) {
            #pragma unroll
            for (int r=0; r<4; ++r) {
                float gr = accg[mt][0][r] + bgv[0];
                float gz = accg[mt][1][r] + bgv[1];
                float gn = accg[mt][2][r] + bgv[2];
                float hr = acch[mt][0][r] + bhv[0];
                float hz = acch[mt][1][r] + bhv[1];
                float hn = acch[mt][2][r] + bhv[2];
                float rr = fsig(gr + hr);
                float zz = fsig(gz + hz);
                float nv = ftanh(gn + rr*hn);
                float hv = Hlds[mt*16 + quad*4 + r][c];
                Glds[mt*16 + quad*4 + r][c] = (bf16)((1.0f - zz)*nv + zz*hv);
            }
        }
        __syncthreads();                                    // (B)

        // ---- stage 2
        if constexpr (MODE == 0) {
            f32x4 acc2[2] = {{0.f,0.f,0.f,0.f},{0.f,0.f,0.f,0.f}};
            #pragma unroll
            for (int ks=0; ks<2; ++ks)
                #pragma unroll
                for (int mt=0; mt<2; ++mt) {
                    bf16x8 a = *(const bf16x8*)&Glds[mt*16+col][ks*32+quad*8];
                    acc2[mt] = __builtin_amdgcn_mfma_f32_16x16x32_bf16(a, B2[ks], acc2[mt], 0,0,0);
                }
            #pragma unroll
            for (int mt=0; mt<2; ++mt)
                #pragma unroll
                for (int r=0; r<4; ++r)
                    Obf[(long)(tb+mt*16+quad*4+r)*HH + 16*w+col] = (bf16)(acc2[mt][r] + b2s);
        } else {
            if (w < 2) {   // 32 rows = 2 waves x 16-row M tiles; C = 16 cols
                f32x4 acc2 = {0.f,0.f,0.f,0.f};
                #pragma unroll
                for (int ks=0; ks<2; ++ks) {
                    bf16x8 a = *(const bf16x8*)&Glds[w*16+col][ks*32+quad*8];
                    acc2 = __builtin_amdgcn_mfma_f32_16x16x32_bf16(a, B2[ks], acc2, 0,0,0);
                }
                #pragma unroll
                for (int r=0; r<4; ++r) {
                    long n = tb + w*16 + quad*4 + r;
                    float val = acc2[r] + b2s;
                    float m = val;
                    #pragma unroll
                    for (int off=8; off>0; off>>=1) m = fmaxf(m, __shfl_xor(m, off, 16));
                    float ex = __expf(val - m);
                    float ssum = ex;
                    #pragma unroll
                    for (int off=8; off>0; off>>=1) ssum += __shfl_xor(ssum, off, 16);
                    Of[n*CC + col] = val - m - __logf(ssum);
                }
            }
        }
    }
}

extern "C" void kernel_launch(void* const* d_in, const int* in_sizes, int n_in,
                              void* d_out, int out_size, void* d_ws, size_t ws_size,
                              hipStream_t stream)
{
    const float* x       = (const float*)d_in[0];
    const int*   ei      = (const int*)  d_in[1];
    const float* ew      = (const float*)d_in[2];
    const int*   ei_re   = (const int*)  d_in[3];
    const float* ew_re   = (const float*)d_in[4];
    const float* W_first = (const float*)d_in[5];
    const float* b_first = (const float*)d_in[6];
    const float* W_con1  = (const float*)d_in[7];
    const float* b_con1  = (const float*)d_in[8];
    const float* W_con2  = (const float*)d_in[9];
    const float* b_con2  = (const float*)d_in[10];
    const float* W_lin1  = (const float*)d_in[11];
    const float* b_lin1  = (const float*)d_in[12];
    const float* W_out   = (const float*)d_in[13];
    const float* b_out   = (const float*)d_in[14];
    const float* W_ih    = (const float*)d_in[15];
    const float* W_hh    = (const float*)d_in[16];
    const float* b_ih    = (const float*)d_in[17];
    const float* b_hh    = (const float*)d_in[18];
    float* out = (float*)d_out;

    // ---- workspace layout (edata BEFORE rp so csr_prop's <=60B edata
    //      overread lands in the live rp array, not past ws)
    float* h    = (float*)d_ws;                // [N*64] fp32 GRU state
    bf16*  x1b  = (bf16*)(h + (long)NN*HH);    // [N*64]
    bf16*  x2b  = x1b + (long)NN*HH;           // [N*64]
    bf16*  hbf  = x2b + (long)NN*HH;           // [N*64]
    bf16*  hAbf = hbf + (long)NN*HH;           // [N*64]
    float* b1 = (float*)(hAbf + (long)NN*HH);  // [192]
    float* b2 = b1 + 192;                      // [192]
    bf16*  W1bf = (bf16*)(b2 + 192);           // [192*128]
    bf16*  W2bf = W1bf + 192*128;
    bf16*  Whbf = W2bf + 192*128;
    bf16*  Wfbf = Whbf + 192*64;
    bf16*  Wlbf = Wfbf + 64*128;
    bf16*  Wobf = Wlbf + 64*64;
    unsigned* edata = (unsigned*)(Wobf + 16*64); // [2E] packed (src,w), dst-sorted
    int*   rp     = (int*)(edata + 2*EE);      // [NSEG+1]  (doubles as edata overread pad)
    int*   bkcnt  = rp + NSEG + 1;             // [NBUK]
    int*   bkcur  = bkcnt + NBUK;              // [NBUK] (adjacent: one memset covers both)
    int*      tmp_d = (int*)x1b;               // [2E] 8 MB (aliases, dead until fillB done)
    unsigned* tmp_p = (unsigned*)x2b;          // [2E] 8 MB

    // 1) bucket-count + weight precomp (merged, independent block ranges)
    hipMemsetAsync(bkcnt, 0, (size_t)(2*NBUK)*sizeof(int), stream);
    count_precomp_kernel<<<P1BLK + PRE_BLK, 256, 0, stream>>>(
        ei, ei_re, bkcnt,
        W_ih, b_ih, W_con1, b_con1, W_con2, b_con2, W_hh, W_first, W_lin1, W_out,
        W1bf, b1, W2bf, b2, Whbf, Wfbf, Wlbf, Wobf);

    // 2) fillA (2-phase sort, phase 1; in-block global-prefix scan)
    fillA_kernel<<<P1BLK, 256, 0, stream>>>(ei, ew, ei_re, ew_re, bkcnt, bkcur, tmp_d, tmp_p);

    // 3) fillB + lin_first (merged: sort phase 2 overlaps the W_first MFMA GEMM)
    fillB_lin_kernel<<<NBUK + LINB, 1024, 0, stream>>>(
        bkcnt, tmp_d, tmp_p, edata, rp, x, Wfbf, b_first, h, hbf);

    // 4) layer-1 propagation (persistent grid, proven inner loop)
    csr_prop_kernel<<<CSRB, 256, 0, stream>>>(hbf, rp, edata, x1b, x2b);

    // 5) fused con1 + GRU + lin1 -> hAbf   (MFMA)
    layer_fused_kernel<0><<<LAYB, 256, 0, stream>>>(x1b, x2b, h, W1bf, b1, Whbf, b_hh,
                                                    Wlbf, b_lin1, hAbf, nullptr);

    // 6) layer-2 propagation
    csr_prop_kernel<<<CSRB, 256, 0, stream>>>(hAbf, rp, edata, x1b, x2b);

    // 7) fused con2 + GRU + W_out + log_softmax -> out   (MFMA)
    layer_fused_kernel<1><<<LAYB, 256, 0, stream>>>(x1b, x2b, h, W2bf, b2, Whbf, b_hh,
                                                    Wobf, b_out, nullptr, out);
}